// Round 12
// baseline (3498.174 us; speedup 1.0000x reference)
//
#include <hip/hip_runtime.h>
#include <hip/hip_bf16.h>
#include <math.h>

#define Bn 4
#define Tn 1024
#define Dn 512
#define Hn 8
#define BHn 32
#define LDP 65   // fp32 LDS stride (pad)
#define LDU 68   // fp32 LDS stride for Ua (16B-aligned rows)
#define LH 72    // fp16 LDS stride in halves
#define TS 32    // momentum scan sub-block (steps)

typedef _Float16 f16x8 __attribute__((ext_vector_type(8)));
typedef _Float16 f16x4 __attribute__((ext_vector_type(4)));
typedef float    f32x4 __attribute__((ext_vector_type(4)));

__constant__ float NS_Ac[6] = {3955.0f/1024.0f, 3735.0f/1024.0f, 3799.0f/1024.0f,
                               4019.0f/1024.0f, 2677.0f/1024.0f, 2172.0f/1024.0f};
__constant__ float NS_Bc[6] = {-8306.0f/1024.0f, -6681.0f/1024.0f, -6499.0f/1024.0f,
                               -6385.0f/1024.0f, -3029.0f/1024.0f, -1833.0f/1024.0f};
__constant__ float NS_Cc[6] = {5008.0f/1024.0f, 3463.0f/1024.0f, 3211.0f/1024.0f,
                               2906.0f/1024.0f, 1162.0f/1024.0f,  682.0f/1024.0f};

__device__ __forceinline__ f32x4 mfma16(f16x4 a, f16x4 b, f32x4 c) {
  return __builtin_amdgcn_mfma_f32_16x16x16f16(a, b, c, 0, 0, 0);
}
// K=32 MFMA; halves of operand = 16-col tiles (2c, 2c+1), k-index 4g+d.
__device__ __forceinline__ f32x4 mfma32(f16x8 a, f16x8 b, f32x4 c) {
  return __builtin_amdgcn_mfma_f32_16x16x32_f16(a, b, c, 0, 0, 0);
}

__device__ __forceinline__ f16x4 cvt4(f32x4 a) {   // RNE scalar converts
  f16x4 h;
  h[0] = (_Float16)a[0]; h[1] = (_Float16)a[1];
  h[2] = (_Float16)a[2]; h[3] = (_Float16)a[3];
  return h;
}

__device__ __forceinline__ f16x4 cvt4rtz(f32x4 a) { // packed RTZ (2 insts)
  const auto lo = __builtin_amdgcn_cvt_pkrtz(a[0], a[1]);  // __fp16 x2
  const auto hi = __builtin_amdgcn_cvt_pkrtz(a[2], a[3]);
  f16x4 h;
  h[0] = (_Float16)lo[0]; h[1] = (_Float16)lo[1];
  h[2] = (_Float16)hi[0]; h[3] = (_Float16)hi[1];
  return h;
}

__device__ __forceinline__ f16x8 pack8(f16x4 lo, f16x4 hi) {
  f16x8 o;
  o[0] = lo[0]; o[1] = lo[1]; o[2] = lo[2]; o[3] = lo[3];
  o[4] = hi[0]; o[5] = hi[1]; o[6] = hi[2]; o[7] = hi[3];
  return o;
}

__device__ __forceinline__ void set_half(f16x8& v, int h, f16x4 x) {
  if (h) { v[4] = x[0]; v[5] = x[1]; v[6] = x[2]; v[7] = x[3]; }
  else   { v[0] = x[0]; v[1] = x[1]; v[2] = x[2]; v[3] = x[3]; }
}

__device__ __forceinline__ f16x4 make_If(int r, int g) {
  const int dd = r - 4 * g;
  f16x4 If;
  If[0] = (dd == 0) ? (_Float16)1.f : (_Float16)0.f;
  If[1] = (dd == 1) ? (_Float16)1.f : (_Float16)0.f;
  If[2] = (dd == 2) ? (_Float16)1.f : (_Float16)0.f;
  If[3] = (dd == 3) ? (_Float16)1.f : (_Float16)0.f;
  return If;
}

// read f16x8 K=32 frag (row, 32-chunk c) from LDS tile [64][LH]
__device__ __forceinline__ f16x8 ld_frag8(const _Float16* lds, int row, int c, int g) {
  const f16x4 lo = *reinterpret_cast<const f16x4*>(lds + row * LH + (2 * c) * 16 + 4 * g);
  const f16x4 hi = *reinterpret_cast<const f16x4*>(lds + row * LH + (2 * c + 1) * 16 + 4 * g);
  return pack8(lo, hi);
}

// Frag-flat layout of a 64x64 matrix (4096 elements):
//   flat(row,col) = chunk*512 + lane*8 + sub
//   chunk = (row>>4)*2 + (col>>5);  lane = ((col&15)>>2)*16 + (row&15)
//   sub   = ((col>>4)&1)*4 + (col&3)

// ---------- staging helpers ----------

__device__ __forceinline__ void stage_tile_h(_Float16* __restrict__ dst,
                                             const float* __restrict__ src,
                                             int srcStride, int tid) {
#pragma unroll
  for (int i = 0; i < 4; ++i) {
    const int idx = tid + (i << 8);
    const int row = idx >> 4;
    const int c4  = (idx & 15) << 2;
    const float4 v = *reinterpret_cast<const float4*>(src + (size_t)row * srcStride + c4);
    f16x4 h;
    h[0] = (_Float16)v.x; h[1] = (_Float16)v.y; h[2] = (_Float16)v.z; h[3] = (_Float16)v.w;
    *reinterpret_cast<f16x4*>(dst + row * LH + c4) = h;
  }
}

__device__ __forceinline__ void stage_tile_u(float* __restrict__ dst,
                                             const float* __restrict__ src, int tid) {
#pragma unroll
  for (int i = 0; i < 4; ++i) {
    const int idx = tid + (i << 8);
    const int row = idx >> 4;
    const int c4  = (idx & 15) << 2;
    *reinterpret_cast<float4*>(dst + row * LDU + c4) =
        *reinterpret_cast<const float4*>(src + (size_t)row * 64 + c4);
  }
}

// Blocked unit-lower-triangular solve
__device__ __forceinline__ void tri_solve_blocked(const float* __restrict__ Sc,
                                                  float* __restrict__ Ua, int tid) {
  const int dv = tid & 63;
  const int grp = tid >> 6;
#pragma unroll 1
  for (int db = 0; db < 4; ++db) {
    const int base = db * 16;
    if (grp == 0) {
#pragma unroll 1
      for (int rr = 1; rr < 16; ++rr) {
        float s = 0.f;
        for (int c = 0; c < rr; ++c)
          s = fmaf(Sc[(base + rr) * LDP + base + c], Ua[(base + c) * LDU + dv], s);
        Ua[(base + rr) * LDU + dv] -= s;
      }
    }
    __syncthreads();
    if (db < 3) {
      for (int r2 = base + 16 + grp; r2 < 64; r2 += 4) {
        float s = 0.f;
#pragma unroll
        for (int c = 0; c < 16; ++c)
          s = fmaf(Sc[r2 * LDP + base + c], Ua[(base + c) * LDU + dv], s);
        Ua[r2 * LDU + dv] -= s;
      }
    }
    __syncthreads();
  }
}

// ---------- kernels ----------

// q/k/v/w projections via fp16 MFMA (K=32)
__global__ __launch_bounds__(256) void proj4_kernel(
    const float* __restrict__ x,
    const float* __restrict__ W0, const float* __restrict__ W1,
    const float* __restrict__ W2, const float* __restrict__ W3,
    float* __restrict__ o0, float* __restrict__ o1,
    float* __restrict__ o2, float* __restrict__ o3) {
  __shared__ __align__(16) _Float16 Af[64 * LH];
  __shared__ __align__(16) _Float16 Bf[64 * LH];
  const float* W; float* outp;
  switch (blockIdx.z) {
    case 0:  W = W0; outp = o0; break;
    case 1:  W = W1; outp = o1; break;
    case 2:  W = W2; outp = o2; break;
    default: W = W3; outp = o3; break;
  }
  const int tid = threadIdx.x;
  const int m0 = blockIdx.x * 64;
  const int n0 = blockIdx.y * 64;
  const int wid = tid >> 6, lane = tid & 63;
  const int r = lane & 15, g = lane >> 4;
  f32x4 acc[4] = {};
  for (int kt = 0; kt < Dn; kt += 64) {
    stage_tile_h(Af, x + (size_t)m0 * Dn + kt, Dn, tid);
    stage_tile_h(Bf, W + (size_t)n0 * Dn + kt, Dn, tid);
    __syncthreads();
    f16x8 a8[2];
#pragma unroll
    for (int c = 0; c < 2; ++c) a8[c] = ld_frag8(Af, 16 * wid + r, c, g);
#pragma unroll
    for (int jb = 0; jb < 4; ++jb) {
#pragma unroll
      for (int c = 0; c < 2; ++c)
        acc[jb] = mfma32(a8[c], ld_frag8(Bf, 16 * jb + r, c, g), acc[jb]);
    }
    __syncthreads();
  }
#pragma unroll
  for (int jb = 0; jb < 4; ++jb)
#pragma unroll
    for (int d = 0; d < 4; ++d) {
      const int m = m0 + 16 * wid + 4 * g + d;
      const int n = n0 + 16 * jb + r;
      const int b = m >> 10, t = m & 1023, h = n >> 6, e = n & 63;
      outp[(((size_t)(b * Hn + h)) * Tn + t) * 64 + e] = acc[jb][d];
    }
}

// eta/theta projection
#define XSTR 516
__global__ __launch_bounds__(256) void wp_kernel(const float* __restrict__ x,
                                                 const float* __restrict__ Wp,
                                                 float* __restrict__ eta,
                                                 float* __restrict__ theta) {
  __shared__ float xs[16 * XSTR];
  __shared__ float wps[16 * XSTR];
  const int tid = threadIdx.x;
  const int r0 = blockIdx.x * 16;
#pragma unroll
  for (int i = 0; i < 8; ++i) {
    const int idx = tid + (i << 8);
    const int r = idx >> 7, c4 = (idx & 127) << 2;
    const float4 v = *reinterpret_cast<const float4*>(x + (size_t)(r0 + r) * Dn + c4);
    float* p = xs + r * XSTR + c4;
    p[0] = v.x; p[1] = v.y; p[2] = v.z; p[3] = v.w;
    const float4 wv = *reinterpret_cast<const float4*>(Wp + (size_t)r * Dn + c4);
    float* pw = wps + r * XSTR + c4;
    pw[0] = wv.x; pw[1] = wv.y; pw[2] = wv.z; pw[3] = wv.w;
  }
  __syncthreads();
  const int row = tid >> 4, col = tid & 15;
  float acc = 0.f;
#pragma unroll 8
  for (int k = 0; k < Dn; ++k) acc = fmaf(xs[row * XSTR + k], wps[col * XSTR + k], acc);
  const float sg = 1.f / (1.f + __expf(-acc));
  const int m = r0 + row, b = m >> 10, t = m & 1023, h = col >> 1;
  float* dst = (col & 1) ? theta : eta;
  dst[((size_t)(b * Hn + h)) * Tn + t] = sg;
}

// Per-row softmax stats via fp16 MFMA (K=32) + wave-parallel flash update.
__global__ __launch_bounds__(256) void rowstats_kernel(
    const float* __restrict__ wb, const float* __restrict__ kb,
    float* __restrict__ rowm, float* __restrict__ rowl) {
  __shared__ __align__(16) _Float16 Wh[64 * LH];
  __shared__ __align__(16) _Float16 Kh[64 * LH];
  const int tb = blockIdx.x, bh = blockIdx.y, t0 = tb * 64;
  const int tid = threadIdx.x, wid = tid >> 6, lane = tid & 63;
  const int r = lane & 15, g = lane >> 4;
  stage_tile_h(Wh, wb + ((size_t)bh * Tn + t0) * 64, 64, tid);
  float rm[4], rl[4];
#pragma unroll
  for (int d = 0; d < 4; ++d) { rm[d] = -INFINITY; rl[d] = 0.f; }
  __syncthreads();
  f16x8 wfr8[2];
#pragma unroll
  for (int c = 0; c < 2; ++c) wfr8[c] = ld_frag8(Wh, 16 * wid + r, c, g);
  for (int sb = 0; sb <= tb; ++sb) {
    __syncthreads();
    stage_tile_h(Kh, kb + ((size_t)bh * Tn + sb * 64) * 64, 64, tid);
    __syncthreads();
    float sv[4][4];
    float tmax[4] = {-INFINITY, -INFINITY, -INFINITY, -INFINITY};
#pragma unroll
    for (int jb = 0; jb < 4; ++jb) {
      f32x4 acc = {0.f, 0.f, 0.f, 0.f};
#pragma unroll
      for (int c = 0; c < 2; ++c)
        acc = mfma32(wfr8[c], ld_frag8(Kh, 16 * jb + r, c, g), acc);
      const int col = sb * 64 + 16 * jb + r;
#pragma unroll
      for (int d = 0; d < 4; ++d) {
        const int row = t0 + 16 * wid + 4 * g + d;
        const float s = (col < row) ? acc[d] * 0.125f : -INFINITY;
        sv[jb][d] = s;
        tmax[d] = fmaxf(tmax[d], s);
      }
    }
#pragma unroll
    for (int m = 1; m < 16; m <<= 1)
#pragma unroll
      for (int d = 0; d < 4; ++d) tmax[d] = fmaxf(tmax[d], __shfl_xor(tmax[d], m, 64));
#pragma unroll
    for (int d = 0; d < 4; ++d) {
      const float mnew  = fmaxf(rm[d], tmax[d]);
      const float msafe = (mnew == -INFINITY) ? 0.f : mnew;
      float s = __expf(sv[0][d] - msafe) + __expf(sv[1][d] - msafe) +
                __expf(sv[2][d] - msafe) + __expf(sv[3][d] - msafe);
#pragma unroll
      for (int m = 1; m < 16; m <<= 1) s += __shfl_xor(s, m, 64);
      const float scale = (rm[d] == -INFINITY) ? 0.f : __expf(rm[d] - msafe);
      rl[d] = rl[d] * scale + s;
      rm[d] = mnew;
    }
  }
  if (r == 0) {
#pragma unroll
    for (int d = 0; d < 4; ++d) {
      const int row = t0 + 16 * wid + 4 * g + d;
      rowm[(size_t)bh * Tn + row] = rm[d];
      rowl[(size_t)bh * Tn + row] = (rl[d] == 0.f) ? 1.f : rl[d];
    }
  }
}

// Ub := vb
__global__ __launch_bounds__(256) void copyU_kernel(const float* __restrict__ vb,
                                                    float* __restrict__ Ub) {
  const int gid = blockIdx.x * 256 + threadIdx.x;
  ((float4*)Ub)[gid] = ((const float4*)vb)[gid];
}

// diagonal solve of block 0 (K=16 path kept)
__global__ __launch_bounds__(256) void solve_diag0_kernel(
    const float* __restrict__ wb, const float* __restrict__ kb,
    const float* __restrict__ vb, const float* __restrict__ rowm,
    const float* __restrict__ rowl, float* __restrict__ Ub) {
  __shared__ __align__(16) _Float16 Wh[64 * LH];
  __shared__ __align__(16) _Float16 Kh[64 * LH];
  __shared__ float Sc[64 * LDP];
  __shared__ __align__(16) float Ua[64 * LDU];
  __shared__ float rmL[64], rlL[64];
  const int bh = blockIdx.x;
  const int tid = threadIdx.x, wid = tid >> 6, lane = tid & 63;
  const int r = lane & 15, g = lane >> 4;
  stage_tile_h(Wh, wb + (size_t)bh * Tn * 64, 64, tid);
  stage_tile_h(Kh, kb + (size_t)bh * Tn * 64, 64, tid);
  stage_tile_u(Ua, vb + (size_t)bh * Tn * 64, tid);
  if (tid < 64) { rmL[tid] = rowm[(size_t)bh * Tn + tid]; rlL[tid] = rowl[(size_t)bh * Tn + tid]; }
  __syncthreads();
  f16x4 wfr[4];
#pragma unroll
  for (int kc = 0; kc < 4; ++kc)
    wfr[kc] = *reinterpret_cast<const f16x4*>(Wh + (16 * wid + r) * LH + kc * 16 + 4 * g);
  float rmv[4], rlv[4];
#pragma unroll
  for (int d = 0; d < 4; ++d) {
    rmv[d] = rmL[16 * wid + 4 * g + d];
    rlv[d] = rlL[16 * wid + 4 * g + d];
  }
#pragma unroll
  for (int jb = 0; jb < 4; ++jb) {
    f32x4 acc = {0.f, 0.f, 0.f, 0.f};
#pragma unroll
    for (int kc = 0; kc < 4; ++kc)
      acc = mfma16(wfr[kc],
                   *reinterpret_cast<const f16x4*>(Kh + (16 * jb + r) * LH + kc * 16 + 4 * g),
                   acc);
#pragma unroll
    for (int d = 0; d < 4; ++d) {
      const int lr = 16 * wid + 4 * g + d, lc = 16 * jb + r;
      Sc[lr * LDP + lc] = (lc < lr) ? __expf(acc[d] * 0.125f - rmv[d]) / rlv[d] : 0.f;
    }
  }
  __syncthreads();
  tri_solve_blocked(Sc, Ua, tid);
#pragma unroll
  for (int i = 0; i < 4; ++i) {
    const int idx = tid + (i << 8);
    const int row = idx >> 4, c4 = (idx & 15) << 2;
    *reinterpret_cast<float4*>(Ub + ((size_t)bh * Tn + row) * 64 + c4) =
        *reinterpret_cast<const float4*>(Ua + row * LDU + c4);
  }
}

// step ib: U[f] -= P[f,ib] @ U[ib]; f==ib+1 also diag-solves (K=16 path kept)
__global__ __launch_bounds__(256) void solve_step_kernel(
    const float* __restrict__ wb, const float* __restrict__ kb,
    const float* __restrict__ rowm, const float* __restrict__ rowl,
    float* __restrict__ Ub, int ib) {
  __shared__ __align__(16) _Float16 Wh[64 * LH];
  __shared__ __align__(16) _Float16 Kh[64 * LH];
  __shared__ __align__(16) _Float16 UTh[64 * LH];
  __shared__ float Sc[64 * LDP];
  __shared__ __align__(16) float Ua[64 * LDU];
  __shared__ float rmL[64], rlL[64];
  const int f = ib + 1 + blockIdx.x, bh = blockIdx.y;
  const int tid = threadIdx.x, wid = tid >> 6, lane = tid & 63;
  const int r = lane & 15, g = lane >> 4;
  stage_tile_h(Wh, wb + ((size_t)bh * Tn + f * 64) * 64, 64, tid);
  stage_tile_h(Kh, kb + ((size_t)bh * Tn + ib * 64) * 64, 64, tid);
  {
    const float* src = Ub + ((size_t)bh * Tn + ib * 64) * 64;
#pragma unroll
    for (int i2 = 0; i2 < 4; ++i2) {
      const int idx = tid + (i2 << 8);
      const int row = idx >> 4, c4 = (idx & 15) << 2;
      const float4 v = *reinterpret_cast<const float4*>(src + (size_t)row * 64 + c4);
      UTh[(c4 + 0) * LH + row] = (_Float16)v.x;
      UTh[(c4 + 1) * LH + row] = (_Float16)v.y;
      UTh[(c4 + 2) * LH + row] = (_Float16)v.z;
      UTh[(c4 + 3) * LH + row] = (_Float16)v.w;
    }
  }
  if (tid < 64) {
    rmL[tid] = rowm[(size_t)bh * Tn + f * 64 + tid];
    rlL[tid] = rowl[(size_t)bh * Tn + f * 64 + tid];
  }
  __syncthreads();
  f16x4 wfr[4];
#pragma unroll
  for (int kc = 0; kc < 4; ++kc)
    wfr[kc] = *reinterpret_cast<const f16x4*>(Wh + (16 * wid + r) * LH + kc * 16 + 4 * g);
  float rmv[4], rlv[4];
#pragma unroll
  for (int d = 0; d < 4; ++d) {
    rmv[d] = rmL[16 * wid + 4 * g + d];
    rlv[d] = rlL[16 * wid + 4 * g + d];
  }
  const f16x4 If = make_If(r, g);
  f16x4 Pfr[4];
#pragma unroll
  for (int jb = 0; jb < 4; ++jb) {
    f32x4 acc = {0.f, 0.f, 0.f, 0.f};
#pragma unroll
    for (int kc = 0; kc < 4; ++kc)
      acc = mfma16(wfr[kc],
                   *reinterpret_cast<const f16x4*>(Kh + (16 * jb + r) * LH + kc * 16 + 4 * g),
                   acc);
    f16x4 pf;
#pragma unroll
    for (int d = 0; d < 4; ++d)
      pf[d] = (_Float16)(-__expf(acc[d] * 0.125f - rmv[d]) / rlv[d]);
    Pfr[jb] = cvt4(mfma16(pf, If, (f32x4){0.f, 0.f, 0.f, 0.f}));
  }
  const float* uf = Ub + ((size_t)bh * Tn + f * 64) * 64;
  f32x4 acc2[4];
#pragma unroll
  for (int i = 0; i < 4; ++i) {
    const float4 v = *reinterpret_cast<const float4*>(uf + (size_t)(16 * wid + r) * 64 + 16 * i + 4 * g);
    acc2[i][0] = v.x; acc2[i][1] = v.y; acc2[i][2] = v.z; acc2[i][3] = v.w;
#pragma unroll
    for (int kc = 0; kc < 4; ++kc)
      acc2[i] = mfma16(*reinterpret_cast<const f16x4*>(UTh + (16 * i + r) * LH + kc * 16 + 4 * g),
                       Pfr[kc], acc2[i]);
  }
  if (f == ib + 1) {
    __syncthreads();
    stage_tile_h(Kh, kb + ((size_t)bh * Tn + f * 64) * 64, 64, tid);
#pragma unroll
    for (int i = 0; i < 4; ++i) {
      float4 v = {acc2[i][0], acc2[i][1], acc2[i][2], acc2[i][3]};
      *reinterpret_cast<float4*>(Ua + (16 * wid + r) * LDU + 16 * i + 4 * g) = v;
    }
    __syncthreads();
#pragma unroll
    for (int jb = 0; jb < 4; ++jb) {
      f32x4 acc = {0.f, 0.f, 0.f, 0.f};
#pragma unroll
      for (int kc = 0; kc < 4; ++kc)
        acc = mfma16(wfr[kc],
                     *reinterpret_cast<const f16x4*>(Kh + (16 * jb + r) * LH + kc * 16 + 4 * g),
                     acc);
#pragma unroll
      for (int d = 0; d < 4; ++d) {
        const int lr = 16 * wid + 4 * g + d, lc = 16 * jb + r;
        Sc[lr * LDP + lc] = (lc < lr) ? __expf(acc[d] * 0.125f - rmv[d]) / rlv[d] : 0.f;
      }
    }
    __syncthreads();
    tri_solve_blocked(Sc, Ua, tid);
#pragma unroll
    for (int i2 = 0; i2 < 4; ++i2) {
      const int idx = tid + (i2 << 8);
      const int row = idx >> 4, c4 = (idx & 15) << 2;
      *reinterpret_cast<float4*>(Ub + ((size_t)bh * Tn + f * 64 + row) * 64 + c4) =
          *reinterpret_cast<const float4*>(Ua + row * LDU + c4);
    }
  } else {
#pragma unroll
    for (int i = 0; i < 4; ++i) {
      float4 v = {acc2[i][0], acc2[i][1], acc2[i][2], acc2[i][3]};
      *reinterpret_cast<float4*>(Ub + ((size_t)bh * Tn + f * 64 + 16 * wid + r) * 64 + 16 * i + 4 * g) = v;
    }
  }
}

// theta block-products: TP[bh][jg] = prod of theta over [jg*TS, (jg+1)*TS)
__global__ __launch_bounds__(256) void thetaprod_kernel(
    const float* __restrict__ theta, float* __restrict__ TP) {
  const int idx = blockIdx.x * 256 + threadIdx.x;   // BHn * (Tn/TS)
  if (idx >= BHn * (Tn / TS)) return;
  const int bh = idx / (Tn / TS), jg = idx % (Tn / TS);
  const float* th = theta + (size_t)bh * Tn + jg * TS;
  float p = 1.f;
#pragma unroll
  for (int s = 0; s < TS; ++s) p *= th[s];
  TP[idx] = p;
}

// Phase A: R_j = recurrence over TS steps from ZERO init. 16 elems/thread.
// Thread tid owns frag-flat elements [tid*16, tid*16+16): two 8-groups,
// chunk = tid>>5, lanes l0 = (2*tid)&63, l1 = l0+1.
__global__ __launch_bounds__(256) void mscanA_kernel(
    const float* __restrict__ Ub, const float* __restrict__ kb,
    const float* __restrict__ theta, float* __restrict__ Rbuf,
    int t0, int Tc) {
  const int j = blockIdx.x, bh = blockIdx.y, tid = threadIdx.x;
  const int nsub = Tc / TS;
  const int chunk = tid >> 5, l0 = (2 * tid) & 63;
  const int i = chunk >> 1, c = chunk & 1, g = l0 >> 4;
  const int dv0 = i * 16 + (l0 & 15);           // even; owns dv0, dv0+1
  const int kbase = c * 32 + g * 4;
  const int tb = t0 + j * TS;
  const float* Urow = Ub + ((size_t)bh * Tn + tb) * 64;
  const float* krow = kb + ((size_t)bh * Tn + tb) * 64;
  const float* th   = theta + (size_t)bh * Tn + tb;
  float M[2][8] = {};
#pragma unroll 2
  for (int st = 0; st < TS; ++st) {
    const float thv = th[st], om = 1.f - thv;
    const float2 uv = *reinterpret_cast<const float2*>(Urow + (size_t)st * 64 + dv0);
    const float4 k0 = *reinterpret_cast<const float4*>(krow + (size_t)st * 64 + kbase);
    const float4 k1 = *reinterpret_cast<const float4*>(krow + (size_t)st * 64 + kbase + 16);
    const float kv[8] = {k0.x, k0.y, k0.z, k0.w, k1.x, k1.y, k1.z, k1.w};
    const float ou[2] = {om * uv.x, om * uv.y};
#pragma unroll
    for (int gq = 0; gq < 2; ++gq)
#pragma unroll
      for (int s = 0; s < 8; ++s)
        M[gq][s] = fmaf(thv, M[gq][s], ou[gq] * kv[s]);
  }
  float* rp = Rbuf + ((size_t)bh * nsub + j) * 4096 + tid * 16;
#pragma unroll
  for (int gq = 0; gq < 2; ++gq)
#pragma unroll
    for (int h = 0; h < 2; ++h) {
      float4 v = {M[gq][h*4], M[gq][h*4+1], M[gq][h*4+2], M[gq][h*4+3]};
      *reinterpret_cast<float4*>(rp + gq * 8 + h * 4) = v;
    }
}

// Phase B: elementwise scan over sub-blocks: Mstart[j] = M; M = TP_j*M + R_j.
__global__ __launch_bounds__(256) void mscanB_kernel(
    float* __restrict__ Mcarry, const float* __restrict__ Rbuf,
    const float* __restrict__ TP, float* __restrict__ Mstart,
    int t0, int Tc) {
  const int gid = blockIdx.x * 256 + threadIdx.x;   // BHn*4096
  const int bh = gid >> 12, p = gid & 4095;
  const int nsub = Tc / TS;
  const int jg0 = t0 / TS;
  float M = Mcarry[gid];
  for (int j = 0; j < nsub; ++j) {
    const size_t idx = ((size_t)bh * nsub + j) * 4096 + p;
    Mstart[idx] = M;
    M = TP[bh * (Tn / TS) + jg0 + j] * M + Rbuf[idx];
  }
  Mcarry[gid] = M;
}

// Phase C: regenerate TS steps from Mstart, write fp16 Mbuf (2 f16x8/step).
__global__ __launch_bounds__(256) void mscanC_kernel(
    const float* __restrict__ Ub, const float* __restrict__ kb,
    const float* __restrict__ theta, const float* __restrict__ Mstart,
    _Float16* __restrict__ Mbuf, int t0, int Tc) {
  const int j = blockIdx.x, bh = blockIdx.y, tid = threadIdx.x;
  const int nsub = Tc / TS;
  const int chunk = tid >> 5, l0 = (2 * tid) & 63;
  const int i = chunk >> 1, c = chunk & 1, g = l0 >> 4;
  const int dv0 = i * 16 + (l0 & 15);
  const int kbase = c * 32 + g * 4;
  const int tb = t0 + j * TS;
  const float* Urow = Ub + ((size_t)bh * Tn + tb) * 64;
  const float* krow = kb + ((size_t)bh * Tn + tb) * 64;
  const float* th   = theta + (size_t)bh * Tn + tb;
  float M[2][8];
  const float* mp = Mstart + ((size_t)bh * nsub + j) * 4096 + tid * 16;
#pragma unroll
  for (int gq = 0; gq < 2; ++gq)
#pragma unroll
    for (int h = 0; h < 2; ++h) {
      const float4 v = *reinterpret_cast<const float4*>(mp + gq * 8 + h * 4);
      M[gq][h*4] = v.x; M[gq][h*4+1] = v.y; M[gq][h*4+2] = v.z; M[gq][h*4+3] = v.w;
    }
#pragma unroll 2
  for (int st = 0; st < TS; ++st) {
    const float thv = th[st], om = 1.f - thv;
    const float2 uv = *reinterpret_cast<const float2*>(Urow + (size_t)st * 64 + dv0);
    const float4 k0 = *reinterpret_cast<const float4*>(krow + (size_t)st * 64 + kbase);
    const float4 k1 = *reinterpret_cast<const float4*>(krow + (size_t)st * 64 + kbase + 16);
    const float kv[8] = {k0.x, k0.y, k0.z, k0.w, k1.x, k1.y, k1.z, k1.w};
    const float ou[2] = {om * uv.x, om * uv.y};
    _Float16* dst = Mbuf + ((size_t)bh * Tc + j * TS + st) * 4096 + tid * 16;
#pragma unroll
    for (int gq = 0; gq < 2; ++gq) {
      f16x8 hh;
#pragma unroll
      for (int s = 0; s < 8; ++s) {
        M[gq][s] = fmaf(thv, M[gq][s], ou[gq] * kv[s]);
        hh[s] = (_Float16)M[gq][s];
      }
      *reinterpret_cast<f16x8*>(dst + gq * 8) = hh;
    }
  }
}

// Newton-Schulz (6 iters), ONE WAVE per 64x64 matrix, register-resident, K=32.
// Zero LDS; frag-flat Mbuf; packed RTZ converts; final X' in RNE.
__global__ __launch_bounds__(256, 8) void ns_kernel(_Float16* __restrict__ Mbuf) {
  const int tid  = threadIdx.x;
  const int wid  = tid >> 6, lane = tid & 63;
  const int r    = lane & 15, g = lane >> 4;
  _Float16* src = Mbuf + ((size_t)blockIdx.x * 4 + wid) * 4096;

  f16x8 Xf8[4][2];
  float ss = 0.f;
#pragma unroll
  for (int i = 0; i < 4; ++i)
#pragma unroll
    for (int c = 0; c < 2; ++c) {
      const f16x8 h = *reinterpret_cast<const f16x8*>(src + (i * 2 + c) * 512 + lane * 8);
#pragma unroll
      for (int d = 0; d < 8; ++d) { const float f = (float)h[d]; ss += f * f; }
      Xf8[i][c] = h;
    }
#pragma unroll
  for (int off = 32; off > 0; off >>= 1) ss += __shfl_xor(ss, off, 64);
  const float inv = 1.f / (sqrtf(ss) + 1e-7f);
#pragma unroll
  for (int i = 0; i < 4; ++i)
#pragma unroll
    for (int c = 0; c < 2; ++c) {
      f32x4 lo, hi;
#pragma unroll
      for (int d = 0; d < 4; ++d) { lo[d] = (float)Xf8[i][c][d] * inv; hi[d] = (float)Xf8[i][c][d + 4] * inv; }
      Xf8[i][c] = pack8(cvt4rtz(lo), cvt4rtz(hi));
    }

  const f16x4 If = make_If(r, g);
  f16x4 zero4;
  zero4[0] = (_Float16)0.f; zero4[1] = (_Float16)0.f;
  zero4[2] = (_Float16)0.f; zero4[3] = (_Float16)0.f;
  const f16x8 I8[2] = {pack8(If, zero4), pack8(zero4, If)};
  float Iw[4];
  Iw[0] = (float)If[0]; Iw[1] = (float)If[1]; Iw[2] = (float)If[2]; Iw[3] = (float)If[3];

  f16x8 Ff8[4][2];
  f32x4 acc[4][4];

#pragma unroll 1
  for (int it = 0; it < 6; ++it) {
    const float ca = NS_Ac[it], cb = NS_Bc[it], cc = NS_Cc[it];
#pragma unroll
    for (int i = 0; i < 4; ++i)
#pragma unroll
      for (int j = i; j < 4; ++j) {
        f32x4 a = mfma32(Xf8[i][0], Xf8[j][0], (f32x4){0.f, 0.f, 0.f, 0.f});
        acc[i][j] = mfma32(Xf8[i][1], Xf8[j][1], a);
      }
#pragma unroll
    for (int i = 0; i < 4; ++i) {
      {
        const f16x4 t = cvt4rtz(mfma32(Xf8[i][i >> 1], I8[i & 1], (f32x4){0.f, 0.f, 0.f, 0.f}));
        set_half(Xf8[i][i >> 1], i & 1, t);
      }
#pragma unroll
      for (int j = i + 1; j < 4; ++j) {
        const f16x4 t1 = cvt4rtz(mfma32(Xf8[i][j >> 1], I8[j & 1], (f32x4){0.f, 0.f, 0.f, 0.f}));
        const f16x4 t2 = cvt4rtz(mfma32(Xf8[j][i >> 1], I8[i & 1], (f32x4){0.f, 0.f, 0.f, 0.f}));
        set_half(Xf8[j][i >> 1], i & 1, t1);
        set_half(Xf8[i][j >> 1], j & 1, t2);
      }
    }
#pragma unroll
    for (int i = 0; i < 4; ++i)
#pragma unroll
      for (int j = i; j < 4; ++j) set_half(Ff8[j][i >> 1], i & 1, cvt4rtz(acc[i][j]));
#pragma unroll
    for (int i = 0; i < 4; ++i)
#pragma unroll
      for (int j = i + 1; j < 4; ++j)
        set_half(Ff8[i][j >> 1], j & 1,
                 cvt4rtz(mfma32(Ff8[j][i >> 1], I8[i & 1], (f32x4){0.f, 0.f, 0.f, 0.f})));
    const float bc = cb / cc;
#pragma unroll
    for (int i = 0; i < 4; ++i)
#pragma unroll
      for (int j = i; j < 4; ++j) {
        f32x4 a = acc[i][j];
        a[0] *= bc; a[1] *= bc; a[2] *= bc; a[3] *= bc;
        a = mfma32(Ff8[i][0], Ff8[j][0], a);
        a = mfma32(Ff8[i][1], Ff8[j][1], a);
        a[0] *= cc; a[1] *= cc; a[2] *= cc; a[3] *= cc;
        acc[i][j] = a;
      }
#pragma unroll
    for (int i = 0; i < 4; ++i)
#pragma unroll
      for (int d = 0; d < 4; ++d) acc[i][i][d] = fmaf(ca, Iw[d], acc[i][i][d]);
#pragma unroll
    for (int i = 0; i < 4; ++i)
#pragma unroll
      for (int j = i; j < 4; ++j) set_half(Ff8[j][i >> 1], i & 1, cvt4rtz(acc[i][j]));
#pragma unroll
    for (int i = 0; i < 4; ++i)
#pragma unroll
      for (int j = i + 1; j < 4; ++j)
        set_half(Ff8[i][j >> 1], j & 1,
                 cvt4rtz(mfma32(Ff8[j][i >> 1], I8[i & 1], (f32x4){0.f, 0.f, 0.f, 0.f})));
#pragma unroll
    for (int i = 0; i < 4; ++i)
#pragma unroll
      for (int j = 0; j < 4; ++j) {
        f32x4 a = mfma32(Xf8[i][0], Ff8[j][0], (f32x4){0.f, 0.f, 0.f, 0.f});
        acc[i][j] = mfma32(Xf8[i][1], Ff8[j][1], a);
      }
    const bool last = (it == 5);
#pragma unroll
    for (int i = 0; i < 4; ++i)
#pragma unroll
      for (int j = 0; j < 4; ++j)
        set_half(Xf8[j][i >> 1], i & 1, last ? cvt4(acc[i][j]) : cvt4rtz(acc[i][j]));
  }

#pragma unroll
  for (int i = 0; i < 4; ++i)
#pragma unroll
    for (int c = 0; c < 2; ++c)
      *reinterpret_cast<f16x8*>(src + (i * 2 + c) * 512 + lane * 8) = Xf8[i][c];
}

// P1: G_j = sum over 16-step subchunk of eta_s * Sp_s (elementwise)
__global__ __launch_bounds__(256) void gsum_kernel(
    const float* __restrict__ eta, const _Float16* __restrict__ Mbuf,
    float* __restrict__ Gbuf, int t0, int Tc) {
  const int j = blockIdx.x, bh = blockIdx.y, tid = threadIdx.x;
  const int nsub = Tc >> 4;
  float acc[16] = {};
#pragma unroll 1
  for (int i = 0; i < 16; ++i) {
    const int tl = j * 16 + i;
    const float ev = eta[(size_t)bh * Tn + t0 + tl];
    const _Float16* sp = Mbuf + ((size_t)bh * Tc + tl) * 4096;
    const f16x8 h0 = *reinterpret_cast<const f16x8*>(sp + tid * 8);
    const f16x8 h1 = *reinterpret_cast<const f16x8*>(sp + 2048 + tid * 8);
#pragma unroll
    for (int u = 0; u < 8; ++u) {
      acc[u]     += ev * (float)h0[u];
      acc[8 + u] += ev * (float)h1[u];
    }
  }
  float* g = Gbuf + ((size_t)bh * nsub + j) * 4096;
#pragma unroll
  for (int u = 0; u < 2; ++u) {
    float4 w0 = {acc[u*4], acc[u*4+1], acc[u*4+2], acc[u*4+3]};
    *reinterpret_cast<float4*>(g + tid * 8 + u * 4) = w0;
    float4 w1 = {acc[8+u*4], acc[8+u*4+1], acc[8+u*4+2], acc[8+u*4+3]};
    *reinterpret_cast<float4*>(g + 2048 + tid * 8 + u * 4) = w1;
  }
}

// P2: scan G over 16-step subchunks -> Sbase_j; updates Scarry (elementwise)
__global__ __launch_bounds__(256) void sbase_kernel(
    float* __restrict__ Scarry, const float* __restrict__ Gbuf,
    float* __restrict__ Sbase, int Tc) {
  const int gid = blockIdx.x * 256 + threadIdx.x;   // BHn*4096
  const int bh = gid >> 12, e = gid & 4095;
  const int nsub = Tc >> 4;
  float S = Scarry[gid];
  for (int j = 0; j < nsub; ++j) {
    const size_t idx = ((size_t)bh * nsub + j) * 4096 + e;
    Sbase[idx] = S;
    S += Gbuf[idx];
  }
  Scarry[gid] = S;
}

// P3: S in registers, 16 steps, shfl_xor reduce. Frag-flat addressing.
__global__ __launch_bounds__(256) void outv2_kernel(
    const float* __restrict__ eta, const float* __restrict__ qb,
    const float* __restrict__ Sbase, const _Float16* __restrict__ Mbuf,
    float* __restrict__ ob, int t0, int Tc) {
  const int j = blockIdx.x, bh = blockIdx.y, tid = threadIdx.x;
  const int nsub = Tc >> 4;
  const int ty = tid >> 4, tx = tid & 15;
  const int dv0 = ty * 4, dk0 = tx * 4;
  int off[4];
#pragma unroll
  for (int r2 = 0; r2 < 4; ++r2) {
    const int row = dv0 + r2;
    off[r2] = ((row >> 4) * 2 + (dk0 >> 5)) * 512 +
              (((dk0 & 15) >> 2) * 16 + (row & 15)) * 8 + ((dk0 >> 4) & 1) * 4;
  }
  float S[4][4];
  const float* sb = Sbase + ((size_t)bh * nsub + j) * 4096;
#pragma unroll
  for (int r2 = 0; r2 < 4; ++r2) {
    const float4 v = *reinterpret_cast<const float4*>(sb + off[r2]);
    S[r2][0] = v.x; S[r2][1] = v.y; S[r2][2] = v.z; S[r2][3] = v.w;
  }
#pragma unroll 1
  for (int i = 0; i < 16; ++i) {
    const int tl = j * 16 + i, t = t0 + tl;
    const float ev = eta[(size_t)bh * Tn + t];
    const float4 q4 = *reinterpret_cast<const float4*>(qb + ((size_t)bh * Tn + t) * 64 + dk0);
    const _Float16* sp = Mbuf + ((size_t)bh * Tc + tl) * 4096;
    float part[4];
#pragma unroll
    for (int r2 = 0; r2 < 4; ++r2) {
      const f16x4 h = *reinterpret_cast<const f16x4*>(sp + off[r2]);
      S[r2][0] += ev * (float)h[0];
      S[r2][1] += ev * (float)h[1];
      S[r2][2] += ev * (float)h[2];
      S[r2][3] += ev * (float)h[3];
      part[r2] = S[r2][0] * q4.x + S[r2][1] * q4.y + S[r2][2] * q4.z + S[r2][3] * q4.w;
    }
#pragma unroll
    for (int m = 1; m < 16; m <<= 1)
#pragma unroll
      for (int r2 = 0; r2 < 4; ++r2) part[r2] += __shfl_xor(part[r2], m, 64);
    if (tx == 0) {
      float4 o4 = {part[0], part[1], part[2], part[3]};
      *reinterpret_cast<float4*>(ob + ((size_t)bh * Tn + t) * 64 + dv0) = o4;
    }
  }
}

// init carries; thread gid owns frag-flat element p -> map to standard (dv,dk)
__global__ __launch_bounds__(256) void init_carry_kernel(
    const float* __restrict__ S0, const float* __restrict__ M0,
    float* __restrict__ Scarry, float* __restrict__ Mcarry) {
  const int gid = blockIdx.x * 256 + threadIdx.x;
  const int h = (gid >> 12) & 7, p = gid & 4095;
  const int q = p >> 9, i = q >> 1, c = q & 1;
  const int l = (p >> 3) & 63, g = l >> 4, r = l & 15;
  const int s = p & 7, jhi = s >> 2, jlo = s & 3;
  const int dv = i * 16 + r;
  const int dk = c * 32 + jhi * 16 + g * 4 + jlo;
  const int e = dv * 64 + dk;
  Scarry[gid] = S0[h * 4096 + e];
  Mcarry[gid] = M0[h * 4096 + e];
}

// final: out = o_flat @ Wo^T via fp16 MFMA (K=32)
__global__ __launch_bounds__(256) void out_gemm_kernel(
    const float* __restrict__ ob, const float* __restrict__ Wo,
    float* __restrict__ out) {
  __shared__ __align__(16) _Float16 Af[64 * LH];
  __shared__ __align__(16) _Float16 Bf[64 * LH];
  const int tid = threadIdx.x;
  const int m0 = blockIdx.x * 64;
  const int n0 = blockIdx.y * 64;
  const int wid = tid >> 6, lane = tid & 63;
  const int r = lane & 15, g = lane >> 4;
  f32x4 acc[4] = {};
  for (int kt = 0; kt < Dn; kt += 64) {
    const int h = kt >> 6;
#pragma unroll
    for (int i = 0; i < 4; ++i) {
      const int idx = tid + (i << 8);
      const int row = idx >> 4, c4 = (idx & 15) << 2;
      const int m = m0 + row, b = m >> 10, t = m & 1023;
      const float4 v = *reinterpret_cast<const float4*>(
          ob + ((size_t)(b * Hn + h) * Tn + t) * 64 + c4);
      f16x4 hv;
      hv[0] = (_Float16)v.x; hv[1] = (_Float16)v.y; hv[2] = (_Float16)v.z; hv[3] = (_Float16)v.w;
      *reinterpret_cast<f16x4*>(Af + row * LH + c4) = hv;
    }
    stage_tile_h(Bf, Wo + (size_t)n0 * Dn + kt, Dn, tid);
    __syncthreads();
    f16x8 a8[2];
#pragma unroll
    for (int c = 0; c < 2; ++c) a8[c] = ld_frag8(Af, 16 * wid + r, c, g);
#pragma unroll
    for (int jb = 0; jb < 4; ++jb) {
#pragma unroll
      for (int c = 0; c < 2; ++c)
        acc[jb] = mfma32(a8[c], ld_frag8(Bf, 16 * jb + r, c, g), acc[jb]);
    }
    __syncthreads();
  }
#pragma unroll
  for (int jb = 0; jb < 4; ++jb)
#pragma unroll
    for (int d = 0; d < 4; ++d) {
      const int m = m0 + 16 * wid + 4 * g + d;
      const int n = n0 + 16 * jb + r;
      out[(size_t)m * Dn + n] = acc[jb][d];
    }
}

// ---------- host ----------

extern "C" void kernel_launch(void* const* d_in, const int* in_sizes, int n_in,
                              void* d_out, int out_size, void* d_ws, size_t ws_size,
                              hipStream_t stream) {
  (void)in_sizes; (void)n_in; (void)out_size;
  const float* x  = (const float*)d_in[0];
  const float* Wq = (const float*)d_in[1];
  const float* Wk = (const float*)d_in[2];
  const float* Wv = (const float*)d_in[3];
  const float* Ww = (const float*)d_in[4];
  const float* Wp = (const float*)d_in[5];
  const float* Wo = (const float*)d_in[6];
  const float* S0 = (const float*)d_in[7];
  const float* M0 = (const float*)d_in[8];
  float* out = (float*)d_out;
  float* ws  = (float*)d_ws;

  size_t off = 0;
  float* qb  = ws + off; off += (size_t)BHn * Tn * 64;
  float* kb  = ws + off; off += (size_t)BHn * Tn * 64;
  float* vb  = ws + off; off += (size_t)BHn * Tn * 64;
  float* wb  = ws + off; off += (size_t)BHn * Tn * 64;
  float* Ub  = ws + off; off += (size_t)BHn * Tn * 64;
  float* ob  = ws + off; off += (size_t)BHn * Tn * 64;
  float* eta   = ws + off; off += (size_t)BHn * Tn;
  float* theta = ws + off; off += (size_t)BHn * Tn;
  float* rowm  = ws + off; off += (size_t)BHn * Tn;
  float* rowl  = ws + off; off += (size_t)BHn * Tn;
  float* Mcarry = ws + off; off += (size_t)BHn * 4096;
  float* Scarry = ws + off; off += (size_t)BHn * 4096;
  float* TP     = ws + off; off += (size_t)BHn * (Tn / TS);

  const size_t avail0 = ws_size / sizeof(float) - off;
  int Tc = 512;
  while (Tc > TS && (size_t)BHn * Tc * 2048 + 2 * (size_t)BHn * (Tc / 16) * 4096 > avail0)
    Tc >>= 1;
  const int nsub = Tc >> 4;        // 16-step subchunks (S-scan)
  const int nsubT = Tc / TS;       // TS-step sub-blocks (M-scan); nsubT <= nsub

  float* Gbuf  = ws + off; off += (size_t)BHn * nsub * 4096;   // aliases Rbuf
  float* Sbase = ws + off; off += (size_t)BHn * nsub * 4096;   // aliases Mstart
  _Float16* Mbuf = (_Float16*)(ws + off);
  float* Rbuf   = Gbuf;    // dead before gsum writes Gbuf
  float* Mstart = Sbase;   // dead before sbase writes Sbase

  hipLaunchKernelGGL(init_carry_kernel, dim3(512), dim3(256), 0, stream, S0, M0, Scarry, Mcarry);
  hipLaunchKernelGGL(proj4_kernel, dim3(64, 8, 4), dim3(256), 0, stream,
                     x, Wq, Wk, Wv, Ww, qb, kb, vb, wb);
  hipLaunchKernelGGL(wp_kernel, dim3(256), dim3(256), 0, stream, x, Wp, eta, theta);
  hipLaunchKernelGGL(thetaprod_kernel, dim3((BHn * (Tn / TS) + 255) / 256), dim3(256), 0, stream,
                     theta, TP);
  hipLaunchKernelGGL(rowstats_kernel, dim3(16, 32), dim3(256), 0, stream, wb, kb, rowm, rowl);
  hipLaunchKernelGGL(copyU_kernel, dim3(2048), dim3(256), 0, stream, vb, Ub);
  hipLaunchKernelGGL(solve_diag0_kernel, dim3(32), dim3(256), 0, stream,
                     wb, kb, vb, rowm, rowl, Ub);
  for (int ib = 0; ib < 15; ++ib) {
    hipLaunchKernelGGL(solve_step_kernel, dim3(15 - ib, 32), dim3(256), 0, stream,
                       wb, kb, rowm, rowl, Ub, ib);
  }

  for (int t0 = 0; t0 < Tn; t0 += Tc) {
    hipLaunchKernelGGL(mscanA_kernel, dim3(nsubT, BHn), dim3(256), 0, stream,
                       Ub, kb, theta, Rbuf, t0, Tc);
    hipLaunchKernelGGL(mscanB_kernel, dim3(512), dim3(256), 0, stream,
                       Mcarry, Rbuf, TP, Mstart, t0, Tc);
    hipLaunchKernelGGL(mscanC_kernel, dim3(nsubT, BHn), dim3(256), 0, stream,
                       Ub, kb, theta, Mstart, Mbuf, t0, Tc);
    hipLaunchKernelGGL(ns_kernel, dim3(BHn * Tc / 4), dim3(256), 0, stream, Mbuf);
    hipLaunchKernelGGL(gsum_kernel, dim3(nsub, BHn), dim3(256), 0, stream,
                       eta, Mbuf, Gbuf, t0, Tc);
    hipLaunchKernelGGL(sbase_kernel, dim3(512), dim3(256), 0, stream, Scarry, Gbuf, Sbase, Tc);
    hipLaunchKernelGGL(outv2_kernel, dim3(nsub, BHn), dim3(256), 0, stream,
                       eta, qb, Sbase, Mbuf, ob, t0, Tc);
  }

  hipLaunchKernelGGL(out_gemm_kernel, dim3(64, 8), dim3(256), 0, stream, ob, Wo, out);
}

// Round 13
// 1126.749 us; speedup vs baseline: 3.1047x; 3.1047x over previous
//
#include <hip/hip_runtime.h>
#include <hip/hip_bf16.h>
#include <math.h>

#define Bn 4
#define Tn 1024
#define Dn 512
#define Hn 8
#define BHn 32
#define LDP 65   // fp32 LDS stride (pad)
#define LDU 68   // fp32 LDS stride for Ua (16B-aligned rows)
#define LH 72    // fp16 LDS stride in halves
#define TS 32    // momentum scan sub-block (steps)

typedef _Float16 f16x8 __attribute__((ext_vector_type(8)));
typedef _Float16 f16x4 __attribute__((ext_vector_type(4)));
typedef float    f32x4 __attribute__((ext_vector_type(4)));

__constant__ float NS_Ac[6] = {3955.0f/1024.0f, 3735.0f/1024.0f, 3799.0f/1024.0f,
                               4019.0f/1024.0f, 2677.0f/1024.0f, 2172.0f/1024.0f};
__constant__ float NS_Bc[6] = {-8306.0f/1024.0f, -6681.0f/1024.0f, -6499.0f/1024.0f,
                               -6385.0f/1024.0f, -3029.0f/1024.0f, -1833.0f/1024.0f};
__constant__ float NS_Cc[6] = {5008.0f/1024.0f, 3463.0f/1024.0f, 3211.0f/1024.0f,
                               2906.0f/1024.0f, 1162.0f/1024.0f,  682.0f/1024.0f};

__device__ __forceinline__ f32x4 mfma16(f16x4 a, f16x4 b, f32x4 c) {
  return __builtin_amdgcn_mfma_f32_16x16x16f16(a, b, c, 0, 0, 0);
}
// K=32 MFMA; halves of operand = 16-col tiles (2c, 2c+1), k-index 4g+d.
__device__ __forceinline__ f32x4 mfma32(f16x8 a, f16x8 b, f32x4 c) {
  return __builtin_amdgcn_mfma_f32_16x16x32_f16(a, b, c, 0, 0, 0);
}

__device__ __forceinline__ f16x4 cvt4(f32x4 a) {   // RNE scalar converts
  f16x4 h;
  h[0] = (_Float16)a[0]; h[1] = (_Float16)a[1];
  h[2] = (_Float16)a[2]; h[3] = (_Float16)a[3];
  return h;
}

__device__ __forceinline__ f16x4 cvt4rtz(f32x4 a) { // packed RTZ (2 insts)
  const auto lo = __builtin_amdgcn_cvt_pkrtz(a[0], a[1]);  // __fp16 x2
  const auto hi = __builtin_amdgcn_cvt_pkrtz(a[2], a[3]);
  f16x4 h;
  h[0] = (_Float16)lo[0]; h[1] = (_Float16)lo[1];
  h[2] = (_Float16)hi[0]; h[3] = (_Float16)hi[1];
  return h;
}

__device__ __forceinline__ f16x8 pack8(f16x4 lo, f16x4 hi) {
  f16x8 o;
  o[0] = lo[0]; o[1] = lo[1]; o[2] = lo[2]; o[3] = lo[3];
  o[4] = hi[0]; o[5] = hi[1]; o[6] = hi[2]; o[7] = hi[3];
  return o;
}

__device__ __forceinline__ void set_half(f16x8& v, int h, f16x4 x) {
  if (h) { v[4] = x[0]; v[5] = x[1]; v[6] = x[2]; v[7] = x[3]; }
  else   { v[0] = x[0]; v[1] = x[1]; v[2] = x[2]; v[3] = x[3]; }
}

__device__ __forceinline__ f16x4 make_If(int r, int g) {
  const int dd = r - 4 * g;
  f16x4 If;
  If[0] = (dd == 0) ? (_Float16)1.f : (_Float16)0.f;
  If[1] = (dd == 1) ? (_Float16)1.f : (_Float16)0.f;
  If[2] = (dd == 2) ? (_Float16)1.f : (_Float16)0.f;
  If[3] = (dd == 3) ? (_Float16)1.f : (_Float16)0.f;
  return If;
}

// read f16x8 K=32 frag (row, 32-chunk c) from LDS tile [64][LH]
__device__ __forceinline__ f16x8 ld_frag8(const _Float16* lds, int row, int c, int g) {
  const f16x4 lo = *reinterpret_cast<const f16x4*>(lds + row * LH + (2 * c) * 16 + 4 * g);
  const f16x4 hi = *reinterpret_cast<const f16x4*>(lds + row * LH + (2 * c + 1) * 16 + 4 * g);
  return pack8(lo, hi);
}

// Frag-flat layout of a 64x64 matrix (4096 elements):
//   flat(row,col) = chunk*512 + lane*8 + sub
//   chunk = (row>>4)*2 + (col>>5);  lane = ((col&15)>>2)*16 + (row&15)
//   sub   = ((col>>4)&1)*4 + (col&3)

// ---------- staging helpers ----------

__device__ __forceinline__ void stage_tile_h(_Float16* __restrict__ dst,
                                             const float* __restrict__ src,
                                             int srcStride, int tid) {
#pragma unroll
  for (int i = 0; i < 4; ++i) {
    const int idx = tid + (i << 8);
    const int row = idx >> 4;
    const int c4  = (idx & 15) << 2;
    const float4 v = *reinterpret_cast<const float4*>(src + (size_t)row * srcStride + c4);
    f16x4 h;
    h[0] = (_Float16)v.x; h[1] = (_Float16)v.y; h[2] = (_Float16)v.z; h[3] = (_Float16)v.w;
    *reinterpret_cast<f16x4*>(dst + row * LH + c4) = h;
  }
}

__device__ __forceinline__ void stage_tile_u(float* __restrict__ dst,
                                             const float* __restrict__ src, int tid) {
#pragma unroll
  for (int i = 0; i < 4; ++i) {
    const int idx = tid + (i << 8);
    const int row = idx >> 4;
    const int c4  = (idx & 15) << 2;
    *reinterpret_cast<float4*>(dst + row * LDU + c4) =
        *reinterpret_cast<const float4*>(src + (size_t)row * 64 + c4);
  }
}

// Blocked unit-lower-triangular solve
__device__ __forceinline__ void tri_solve_blocked(const float* __restrict__ Sc,
                                                  float* __restrict__ Ua, int tid) {
  const int dv = tid & 63;
  const int grp = tid >> 6;
#pragma unroll 1
  for (int db = 0; db < 4; ++db) {
    const int base = db * 16;
    if (grp == 0) {
#pragma unroll 1
      for (int rr = 1; rr < 16; ++rr) {
        float s = 0.f;
        for (int c = 0; c < rr; ++c)
          s = fmaf(Sc[(base + rr) * LDP + base + c], Ua[(base + c) * LDU + dv], s);
        Ua[(base + rr) * LDU + dv] -= s;
      }
    }
    __syncthreads();
    if (db < 3) {
      for (int r2 = base + 16 + grp; r2 < 64; r2 += 4) {
        float s = 0.f;
#pragma unroll
        for (int c = 0; c < 16; ++c)
          s = fmaf(Sc[r2 * LDP + base + c], Ua[(base + c) * LDU + dv], s);
        Ua[r2 * LDU + dv] -= s;
      }
    }
    __syncthreads();
  }
}

// ---------- kernels ----------

// q/k/v/w projections via fp16 MFMA (K=32)
__global__ __launch_bounds__(256) void proj4_kernel(
    const float* __restrict__ x,
    const float* __restrict__ W0, const float* __restrict__ W1,
    const float* __restrict__ W2, const float* __restrict__ W3,
    float* __restrict__ o0, float* __restrict__ o1,
    float* __restrict__ o2, float* __restrict__ o3) {
  __shared__ __align__(16) _Float16 Af[64 * LH];
  __shared__ __align__(16) _Float16 Bf[64 * LH];
  const float* W; float* outp;
  switch (blockIdx.z) {
    case 0:  W = W0; outp = o0; break;
    case 1:  W = W1; outp = o1; break;
    case 2:  W = W2; outp = o2; break;
    default: W = W3; outp = o3; break;
  }
  const int tid = threadIdx.x;
  const int m0 = blockIdx.x * 64;
  const int n0 = blockIdx.y * 64;
  const int wid = tid >> 6, lane = tid & 63;
  const int r = lane & 15, g = lane >> 4;
  f32x4 acc[4] = {};
  for (int kt = 0; kt < Dn; kt += 64) {
    stage_tile_h(Af, x + (size_t)m0 * Dn + kt, Dn, tid);
    stage_tile_h(Bf, W + (size_t)n0 * Dn + kt, Dn, tid);
    __syncthreads();
    f16x8 a8[2];
#pragma unroll
    for (int c = 0; c < 2; ++c) a8[c] = ld_frag8(Af, 16 * wid + r, c, g);
#pragma unroll
    for (int jb = 0; jb < 4; ++jb) {
#pragma unroll
      for (int c = 0; c < 2; ++c)
        acc[jb] = mfma32(a8[c], ld_frag8(Bf, 16 * jb + r, c, g), acc[jb]);
    }
    __syncthreads();
  }
#pragma unroll
  for (int jb = 0; jb < 4; ++jb)
#pragma unroll
    for (int d = 0; d < 4; ++d) {
      const int m = m0 + 16 * wid + 4 * g + d;
      const int n = n0 + 16 * jb + r;
      const int b = m >> 10, t = m & 1023, h = n >> 6, e = n & 63;
      outp[(((size_t)(b * Hn + h)) * Tn + t) * 64 + e] = acc[jb][d];
    }
}

// eta/theta projection
#define XSTR 516
__global__ __launch_bounds__(256) void wp_kernel(const float* __restrict__ x,
                                                 const float* __restrict__ Wp,
                                                 float* __restrict__ eta,
                                                 float* __restrict__ theta) {
  __shared__ float xs[16 * XSTR];
  __shared__ float wps[16 * XSTR];
  const int tid = threadIdx.x;
  const int r0 = blockIdx.x * 16;
#pragma unroll
  for (int i = 0; i < 8; ++i) {
    const int idx = tid + (i << 8);
    const int r = idx >> 7, c4 = (idx & 127) << 2;
    const float4 v = *reinterpret_cast<const float4*>(x + (size_t)(r0 + r) * Dn + c4);
    float* p = xs + r * XSTR + c4;
    p[0] = v.x; p[1] = v.y; p[2] = v.z; p[3] = v.w;
    const float4 wv = *reinterpret_cast<const float4*>(Wp + (size_t)r * Dn + c4);
    float* pw = wps + r * XSTR + c4;
    pw[0] = wv.x; pw[1] = wv.y; pw[2] = wv.z; pw[3] = wv.w;
  }
  __syncthreads();
  const int row = tid >> 4, col = tid & 15;
  float acc = 0.f;
#pragma unroll 8
  for (int k = 0; k < Dn; ++k) acc = fmaf(xs[row * XSTR + k], wps[col * XSTR + k], acc);
  const float sg = 1.f / (1.f + __expf(-acc));
  const int m = r0 + row, b = m >> 10, t = m & 1023, h = col >> 1;
  float* dst = (col & 1) ? theta : eta;
  dst[((size_t)(b * Hn + h)) * Tn + t] = sg;
}

// Per-row softmax stats via fp16 MFMA (K=32) + wave-parallel flash update.
__global__ __launch_bounds__(256) void rowstats_kernel(
    const float* __restrict__ wb, const float* __restrict__ kb,
    float* __restrict__ rowm, float* __restrict__ rowl) {
  __shared__ __align__(16) _Float16 Wh[64 * LH];
  __shared__ __align__(16) _Float16 Kh[64 * LH];
  const int tb = blockIdx.x, bh = blockIdx.y, t0 = tb * 64;
  const int tid = threadIdx.x, wid = tid >> 6, lane = tid & 63;
  const int r = lane & 15, g = lane >> 4;
  stage_tile_h(Wh, wb + ((size_t)bh * Tn + t0) * 64, 64, tid);
  float rm[4], rl[4];
#pragma unroll
  for (int d = 0; d < 4; ++d) { rm[d] = -INFINITY; rl[d] = 0.f; }
  __syncthreads();
  f16x8 wfr8[2];
#pragma unroll
  for (int c = 0; c < 2; ++c) wfr8[c] = ld_frag8(Wh, 16 * wid + r, c, g);
  for (int sb = 0; sb <= tb; ++sb) {
    __syncthreads();
    stage_tile_h(Kh, kb + ((size_t)bh * Tn + sb * 64) * 64, 64, tid);
    __syncthreads();
    float sv[4][4];
    float tmax[4] = {-INFINITY, -INFINITY, -INFINITY, -INFINITY};
#pragma unroll
    for (int jb = 0; jb < 4; ++jb) {
      f32x4 acc = {0.f, 0.f, 0.f, 0.f};
#pragma unroll
      for (int c = 0; c < 2; ++c)
        acc = mfma32(wfr8[c], ld_frag8(Kh, 16 * jb + r, c, g), acc);
      const int col = sb * 64 + 16 * jb + r;
#pragma unroll
      for (int d = 0; d < 4; ++d) {
        const int row = t0 + 16 * wid + 4 * g + d;
        const float s = (col < row) ? acc[d] * 0.125f : -INFINITY;
        sv[jb][d] = s;
        tmax[d] = fmaxf(tmax[d], s);
      }
    }
#pragma unroll
    for (int m = 1; m < 16; m <<= 1)
#pragma unroll
      for (int d = 0; d < 4; ++d) tmax[d] = fmaxf(tmax[d], __shfl_xor(tmax[d], m, 64));
#pragma unroll
    for (int d = 0; d < 4; ++d) {
      const float mnew  = fmaxf(rm[d], tmax[d]);
      const float msafe = (mnew == -INFINITY) ? 0.f : mnew;
      float s = __expf(sv[0][d] - msafe) + __expf(sv[1][d] - msafe) +
                __expf(sv[2][d] - msafe) + __expf(sv[3][d] - msafe);
#pragma unroll
      for (int m = 1; m < 16; m <<= 1) s += __shfl_xor(s, m, 64);
      const float scale = (rm[d] == -INFINITY) ? 0.f : __expf(rm[d] - msafe);
      rl[d] = rl[d] * scale + s;
      rm[d] = mnew;
    }
  }
  if (r == 0) {
#pragma unroll
    for (int d = 0; d < 4; ++d) {
      const int row = t0 + 16 * wid + 4 * g + d;
      rowm[(size_t)bh * Tn + row] = rm[d];
      rowl[(size_t)bh * Tn + row] = (rl[d] == 0.f) ? 1.f : rl[d];
    }
  }
}

// Ub := vb
__global__ __launch_bounds__(256) void copyU_kernel(const float* __restrict__ vb,
                                                    float* __restrict__ Ub) {
  const int gid = blockIdx.x * 256 + threadIdx.x;
  ((float4*)Ub)[gid] = ((const float4*)vb)[gid];
}

// diagonal solve of block 0 (K=16 path kept)
__global__ __launch_bounds__(256) void solve_diag0_kernel(
    const float* __restrict__ wb, const float* __restrict__ kb,
    const float* __restrict__ vb, const float* __restrict__ rowm,
    const float* __restrict__ rowl, float* __restrict__ Ub) {
  __shared__ __align__(16) _Float16 Wh[64 * LH];
  __shared__ __align__(16) _Float16 Kh[64 * LH];
  __shared__ float Sc[64 * LDP];
  __shared__ __align__(16) float Ua[64 * LDU];
  __shared__ float rmL[64], rlL[64];
  const int bh = blockIdx.x;
  const int tid = threadIdx.x, wid = tid >> 6, lane = tid & 63;
  const int r = lane & 15, g = lane >> 4;
  stage_tile_h(Wh, wb + (size_t)bh * Tn * 64, 64, tid);
  stage_tile_h(Kh, kb + (size_t)bh * Tn * 64, 64, tid);
  stage_tile_u(Ua, vb + (size_t)bh * Tn * 64, tid);
  if (tid < 64) { rmL[tid] = rowm[(size_t)bh * Tn + tid]; rlL[tid] = rowl[(size_t)bh * Tn + tid]; }
  __syncthreads();
  f16x4 wfr[4];
#pragma unroll
  for (int kc = 0; kc < 4; ++kc)
    wfr[kc] = *reinterpret_cast<const f16x4*>(Wh + (16 * wid + r) * LH + kc * 16 + 4 * g);
  float rmv[4], rlv[4];
#pragma unroll
  for (int d = 0; d < 4; ++d) {
    rmv[d] = rmL[16 * wid + 4 * g + d];
    rlv[d] = rlL[16 * wid + 4 * g + d];
  }
#pragma unroll
  for (int jb = 0; jb < 4; ++jb) {
    f32x4 acc = {0.f, 0.f, 0.f, 0.f};
#pragma unroll
    for (int kc = 0; kc < 4; ++kc)
      acc = mfma16(wfr[kc],
                   *reinterpret_cast<const f16x4*>(Kh + (16 * jb + r) * LH + kc * 16 + 4 * g),
                   acc);
#pragma unroll
    for (int d = 0; d < 4; ++d) {
      const int lr = 16 * wid + 4 * g + d, lc = 16 * jb + r;
      Sc[lr * LDP + lc] = (lc < lr) ? __expf(acc[d] * 0.125f - rmv[d]) / rlv[d] : 0.f;
    }
  }
  __syncthreads();
  tri_solve_blocked(Sc, Ua, tid);
#pragma unroll
  for (int i = 0; i < 4; ++i) {
    const int idx = tid + (i << 8);
    const int row = idx >> 4, c4 = (idx & 15) << 2;
    *reinterpret_cast<float4*>(Ub + ((size_t)bh * Tn + row) * 64 + c4) =
        *reinterpret_cast<const float4*>(Ua + row * LDU + c4);
  }
}

// step ib: U[f] -= P[f,ib] @ U[ib]; f==ib+1 also diag-solves (K=16 path kept)
__global__ __launch_bounds__(256) void solve_step_kernel(
    const float* __restrict__ wb, const float* __restrict__ kb,
    const float* __restrict__ rowm, const float* __restrict__ rowl,
    float* __restrict__ Ub, int ib) {
  __shared__ __align__(16) _Float16 Wh[64 * LH];
  __shared__ __align__(16) _Float16 Kh[64 * LH];
  __shared__ __align__(16) _Float16 UTh[64 * LH];
  __shared__ float Sc[64 * LDP];
  __shared__ __align__(16) float Ua[64 * LDU];
  __shared__ float rmL[64], rlL[64];
  const int f = ib + 1 + blockIdx.x, bh = blockIdx.y;
  const int tid = threadIdx.x, wid = tid >> 6, lane = tid & 63;
  const int r = lane & 15, g = lane >> 4;
  stage_tile_h(Wh, wb + ((size_t)bh * Tn + f * 64) * 64, 64, tid);
  stage_tile_h(Kh, kb + ((size_t)bh * Tn + ib * 64) * 64, 64, tid);
  {
    const float* src = Ub + ((size_t)bh * Tn + ib * 64) * 64;
#pragma unroll
    for (int i2 = 0; i2 < 4; ++i2) {
      const int idx = tid + (i2 << 8);
      const int row = idx >> 4, c4 = (idx & 15) << 2;
      const float4 v = *reinterpret_cast<const float4*>(src + (size_t)row * 64 + c4);
      UTh[(c4 + 0) * LH + row] = (_Float16)v.x;
      UTh[(c4 + 1) * LH + row] = (_Float16)v.y;
      UTh[(c4 + 2) * LH + row] = (_Float16)v.z;
      UTh[(c4 + 3) * LH + row] = (_Float16)v.w;
    }
  }
  if (tid < 64) {
    rmL[tid] = rowm[(size_t)bh * Tn + f * 64 + tid];
    rlL[tid] = rowl[(size_t)bh * Tn + f * 64 + tid];
  }
  __syncthreads();
  f16x4 wfr[4];
#pragma unroll
  for (int kc = 0; kc < 4; ++kc)
    wfr[kc] = *reinterpret_cast<const f16x4*>(Wh + (16 * wid + r) * LH + kc * 16 + 4 * g);
  float rmv[4], rlv[4];
#pragma unroll
  for (int d = 0; d < 4; ++d) {
    rmv[d] = rmL[16 * wid + 4 * g + d];
    rlv[d] = rlL[16 * wid + 4 * g + d];
  }
  const f16x4 If = make_If(r, g);
  f16x4 Pfr[4];
#pragma unroll
  for (int jb = 0; jb < 4; ++jb) {
    f32x4 acc = {0.f, 0.f, 0.f, 0.f};
#pragma unroll
    for (int kc = 0; kc < 4; ++kc)
      acc = mfma16(wfr[kc],
                   *reinterpret_cast<const f16x4*>(Kh + (16 * jb + r) * LH + kc * 16 + 4 * g),
                   acc);
    f16x4 pf;
#pragma unroll
    for (int d = 0; d < 4; ++d)
      pf[d] = (_Float16)(-__expf(acc[d] * 0.125f - rmv[d]) / rlv[d]);
    Pfr[jb] = cvt4(mfma16(pf, If, (f32x4){0.f, 0.f, 0.f, 0.f}));
  }
  const float* uf = Ub + ((size_t)bh * Tn + f * 64) * 64;
  f32x4 acc2[4];
#pragma unroll
  for (int i = 0; i < 4; ++i) {
    const float4 v = *reinterpret_cast<const float4*>(uf + (size_t)(16 * wid + r) * 64 + 16 * i + 4 * g);
    acc2[i][0] = v.x; acc2[i][1] = v.y; acc2[i][2] = v.z; acc2[i][3] = v.w;
#pragma unroll
    for (int kc = 0; kc < 4; ++kc)
      acc2[i] = mfma16(*reinterpret_cast<const f16x4*>(UTh + (16 * i + r) * LH + kc * 16 + 4 * g),
                       Pfr[kc], acc2[i]);
  }
  if (f == ib + 1) {
    __syncthreads();
    stage_tile_h(Kh, kb + ((size_t)bh * Tn + f * 64) * 64, 64, tid);
#pragma unroll
    for (int i = 0; i < 4; ++i) {
      float4 v = {acc2[i][0], acc2[i][1], acc2[i][2], acc2[i][3]};
      *reinterpret_cast<float4*>(Ua + (16 * wid + r) * LDU + 16 * i + 4 * g) = v;
    }
    __syncthreads();
#pragma unroll
    for (int jb = 0; jb < 4; ++jb) {
      f32x4 acc = {0.f, 0.f, 0.f, 0.f};
#pragma unroll
      for (int kc = 0; kc < 4; ++kc)
        acc = mfma16(wfr[kc],
                     *reinterpret_cast<const f16x4*>(Kh + (16 * jb + r) * LH + kc * 16 + 4 * g),
                     acc);
#pragma unroll
      for (int d = 0; d < 4; ++d) {
        const int lr = 16 * wid + 4 * g + d, lc = 16 * jb + r;
        Sc[lr * LDP + lc] = (lc < lr) ? __expf(acc[d] * 0.125f - rmv[d]) / rlv[d] : 0.f;
      }
    }
    __syncthreads();
    tri_solve_blocked(Sc, Ua, tid);
#pragma unroll
    for (int i2 = 0; i2 < 4; ++i2) {
      const int idx = tid + (i2 << 8);
      const int row = idx >> 4, c4 = (idx & 15) << 2;
      *reinterpret_cast<float4*>(Ub + ((size_t)bh * Tn + f * 64 + row) * 64 + c4) =
          *reinterpret_cast<const float4*>(Ua + row * LDU + c4);
    }
  } else {
#pragma unroll
    for (int i = 0; i < 4; ++i) {
      float4 v = {acc2[i][0], acc2[i][1], acc2[i][2], acc2[i][3]};
      *reinterpret_cast<float4*>(Ub + ((size_t)bh * Tn + f * 64 + 16 * wid + r) * 64 + 16 * i + 4 * g) = v;
    }
  }
}

// theta block-products: TP[bh][jg] = prod of theta over [jg*TS, (jg+1)*TS)
__global__ __launch_bounds__(256) void thetaprod_kernel(
    const float* __restrict__ theta, float* __restrict__ TP) {
  const int idx = blockIdx.x * 256 + threadIdx.x;   // BHn * (Tn/TS)
  if (idx >= BHn * (Tn / TS)) return;
  const int bh = idx / (Tn / TS), jg = idx % (Tn / TS);
  const float* th = theta + (size_t)bh * Tn + jg * TS;
  float p = 1.f;
#pragma unroll
  for (int s = 0; s < TS; ++s) p *= th[s];
  TP[idx] = p;
}

// Phase A: R_j = recurrence over TS steps from ZERO init. 16 elems/thread.
__global__ __launch_bounds__(256) void mscanA_kernel(
    const float* __restrict__ Ub, const float* __restrict__ kb,
    const float* __restrict__ theta, float* __restrict__ Rbuf,
    int t0, int Tc) {
  const int j = blockIdx.x, bh = blockIdx.y, tid = threadIdx.x;
  const int nsub = Tc / TS;
  const int chunk = tid >> 5, l0 = (2 * tid) & 63;
  const int i = chunk >> 1, c = chunk & 1, g = l0 >> 4;
  const int dv0 = i * 16 + (l0 & 15);           // even; owns dv0, dv0+1
  const int kbase = c * 32 + g * 4;
  const int tb = t0 + j * TS;
  const float* Urow = Ub + ((size_t)bh * Tn + tb) * 64;
  const float* krow = kb + ((size_t)bh * Tn + tb) * 64;
  const float* th   = theta + (size_t)bh * Tn + tb;
  float M[2][8] = {};
#pragma unroll 2
  for (int st = 0; st < TS; ++st) {
    const float thv = th[st], om = 1.f - thv;
    const float2 uv = *reinterpret_cast<const float2*>(Urow + (size_t)st * 64 + dv0);
    const float4 k0 = *reinterpret_cast<const float4*>(krow + (size_t)st * 64 + kbase);
    const float4 k1 = *reinterpret_cast<const float4*>(krow + (size_t)st * 64 + kbase + 16);
    const float kv[8] = {k0.x, k0.y, k0.z, k0.w, k1.x, k1.y, k1.z, k1.w};
    const float ou[2] = {om * uv.x, om * uv.y};
#pragma unroll
    for (int gq = 0; gq < 2; ++gq)
#pragma unroll
      for (int s = 0; s < 8; ++s)
        M[gq][s] = fmaf(thv, M[gq][s], ou[gq] * kv[s]);
  }
  float* rp = Rbuf + ((size_t)bh * nsub + j) * 4096 + tid * 16;
#pragma unroll
  for (int gq = 0; gq < 2; ++gq)
#pragma unroll
    for (int h = 0; h < 2; ++h) {
      float4 v = {M[gq][h*4], M[gq][h*4+1], M[gq][h*4+2], M[gq][h*4+3]};
      *reinterpret_cast<float4*>(rp + gq * 8 + h * 4) = v;
    }
}

// Phase B: elementwise scan over sub-blocks: Mstart[j] = M; M = TP_j*M + R_j.
__global__ __launch_bounds__(256) void mscanB_kernel(
    float* __restrict__ Mcarry, const float* __restrict__ Rbuf,
    const float* __restrict__ TP, float* __restrict__ Mstart,
    int t0, int Tc) {
  const int gid = blockIdx.x * 256 + threadIdx.x;   // BHn*4096
  const int bh = gid >> 12, p = gid & 4095;
  const int nsub = Tc / TS;
  const int jg0 = t0 / TS;
  float M = Mcarry[gid];
  for (int j = 0; j < nsub; ++j) {
    const size_t idx = ((size_t)bh * nsub + j) * 4096 + p;
    Mstart[idx] = M;
    M = TP[bh * (Tn / TS) + jg0 + j] * M + Rbuf[idx];
  }
  Mcarry[gid] = M;
}

// Phase C: regenerate TS steps from Mstart, write fp16 Mbuf (2 f16x8/step).
__global__ __launch_bounds__(256) void mscanC_kernel(
    const float* __restrict__ Ub, const float* __restrict__ kb,
    const float* __restrict__ theta, const float* __restrict__ Mstart,
    _Float16* __restrict__ Mbuf, int t0, int Tc) {
  const int j = blockIdx.x, bh = blockIdx.y, tid = threadIdx.x;
  const int nsub = Tc / TS;
  const int chunk = tid >> 5, l0 = (2 * tid) & 63;
  const int i = chunk >> 1, c = chunk & 1, g = l0 >> 4;
  const int dv0 = i * 16 + (l0 & 15);
  const int kbase = c * 32 + g * 4;
  const int tb = t0 + j * TS;
  const float* Urow = Ub + ((size_t)bh * Tn + tb) * 64;
  const float* krow = kb + ((size_t)bh * Tn + tb) * 64;
  const float* th   = theta + (size_t)bh * Tn + tb;
  float M[2][8];
  const float* mp = Mstart + ((size_t)bh * nsub + j) * 4096 + tid * 16;
#pragma unroll
  for (int gq = 0; gq < 2; ++gq)
#pragma unroll
    for (int h = 0; h < 2; ++h) {
      const float4 v = *reinterpret_cast<const float4*>(mp + gq * 8 + h * 4);
      M[gq][h*4] = v.x; M[gq][h*4+1] = v.y; M[gq][h*4+2] = v.z; M[gq][h*4+3] = v.w;
    }
#pragma unroll 2
  for (int st = 0; st < TS; ++st) {
    const float thv = th[st], om = 1.f - thv;
    const float2 uv = *reinterpret_cast<const float2*>(Urow + (size_t)st * 64 + dv0);
    const float4 k0 = *reinterpret_cast<const float4*>(krow + (size_t)st * 64 + kbase);
    const float4 k1 = *reinterpret_cast<const float4*>(krow + (size_t)st * 64 + kbase + 16);
    const float kv[8] = {k0.x, k0.y, k0.z, k0.w, k1.x, k1.y, k1.z, k1.w};
    const float ou[2] = {om * uv.x, om * uv.y};
    _Float16* dst = Mbuf + ((size_t)bh * Tc + j * TS + st) * 4096 + tid * 16;
#pragma unroll
    for (int gq = 0; gq < 2; ++gq) {
      f16x8 hh;
#pragma unroll
      for (int s = 0; s < 8; ++s) {
        M[gq][s] = fmaf(thv, M[gq][s], ou[gq] * kv[s]);
        hh[s] = (_Float16)M[gq][s];
      }
      *reinterpret_cast<f16x8*>(dst + gq * 8) = hh;
    }
  }
}

// Newton-Schulz (6 iters), ONE WAVE per 64x64 matrix, register-resident, K=32.
// Zero LDS; frag-flat Mbuf; packed RTZ converts; final X' in RNE.
// NOTE: needs ~130 VGPR -> min-waves 4 (cap 128, mild pressure) NOT 8 (cap 64 -> spills).
__global__ __launch_bounds__(256, 4) void ns_kernel(_Float16* __restrict__ Mbuf) {
  const int tid  = threadIdx.x;
  const int wid  = tid >> 6, lane = tid & 63;
  const int r    = lane & 15, g = lane >> 4;
  _Float16* src = Mbuf + ((size_t)blockIdx.x * 4 + wid) * 4096;

  f16x8 Xf8[4][2];
  float ss = 0.f;
#pragma unroll
  for (int i = 0; i < 4; ++i)
#pragma unroll
    for (int c = 0; c < 2; ++c) {
      const f16x8 h = *reinterpret_cast<const f16x8*>(src + (i * 2 + c) * 512 + lane * 8);
#pragma unroll
      for (int d = 0; d < 8; ++d) { const float f = (float)h[d]; ss += f * f; }
      Xf8[i][c] = h;
    }
#pragma unroll
  for (int off = 32; off > 0; off >>= 1) ss += __shfl_xor(ss, off, 64);
  const float inv = 1.f / (sqrtf(ss) + 1e-7f);
#pragma unroll
  for (int i = 0; i < 4; ++i)
#pragma unroll
    for (int c = 0; c < 2; ++c) {
      f32x4 lo, hi;
#pragma unroll
      for (int d = 0; d < 4; ++d) { lo[d] = (float)Xf8[i][c][d] * inv; hi[d] = (float)Xf8[i][c][d + 4] * inv; }
      Xf8[i][c] = pack8(cvt4rtz(lo), cvt4rtz(hi));
    }

  const f16x4 If = make_If(r, g);
  f16x4 zero4;
  zero4[0] = (_Float16)0.f; zero4[1] = (_Float16)0.f;
  zero4[2] = (_Float16)0.f; zero4[3] = (_Float16)0.f;
  const f16x8 I8[2] = {pack8(If, zero4), pack8(zero4, If)};
  float Iw[4];
  Iw[0] = (float)If[0]; Iw[1] = (float)If[1]; Iw[2] = (float)If[2]; Iw[3] = (float)If[3];

  f16x8 Ff8[4][2];
  f32x4 acc[4][4];

#pragma unroll 1
  for (int it = 0; it < 6; ++it) {
    const float ca = NS_Ac[it], cb = NS_Bc[it], cc = NS_Cc[it];
#pragma unroll
    for (int i = 0; i < 4; ++i)
#pragma unroll
      for (int j = i; j < 4; ++j) {
        f32x4 a = mfma32(Xf8[i][0], Xf8[j][0], (f32x4){0.f, 0.f, 0.f, 0.f});
        acc[i][j] = mfma32(Xf8[i][1], Xf8[j][1], a);
      }
#pragma unroll
    for (int i = 0; i < 4; ++i) {
      {
        const f16x4 t = cvt4rtz(mfma32(Xf8[i][i >> 1], I8[i & 1], (f32x4){0.f, 0.f, 0.f, 0.f}));
        set_half(Xf8[i][i >> 1], i & 1, t);
      }
#pragma unroll
      for (int j = i + 1; j < 4; ++j) {
        const f16x4 t1 = cvt4rtz(mfma32(Xf8[i][j >> 1], I8[j & 1], (f32x4){0.f, 0.f, 0.f, 0.f}));
        const f16x4 t2 = cvt4rtz(mfma32(Xf8[j][i >> 1], I8[i & 1], (f32x4){0.f, 0.f, 0.f, 0.f}));
        set_half(Xf8[j][i >> 1], i & 1, t1);
        set_half(Xf8[i][j >> 1], j & 1, t2);
      }
    }
#pragma unroll
    for (int i = 0; i < 4; ++i)
#pragma unroll
      for (int j = i; j < 4; ++j) set_half(Ff8[j][i >> 1], i & 1, cvt4rtz(acc[i][j]));
#pragma unroll
    for (int i = 0; i < 4; ++i)
#pragma unroll
      for (int j = i + 1; j < 4; ++j)
        set_half(Ff8[i][j >> 1], j & 1,
                 cvt4rtz(mfma32(Ff8[j][i >> 1], I8[i & 1], (f32x4){0.f, 0.f, 0.f, 0.f})));
    const float bc = cb / cc;
#pragma unroll
    for (int i = 0; i < 4; ++i)
#pragma unroll
      for (int j = i; j < 4; ++j) {
        f32x4 a = acc[i][j];
        a[0] *= bc; a[1] *= bc; a[2] *= bc; a[3] *= bc;
        a = mfma32(Ff8[i][0], Ff8[j][0], a);
        a = mfma32(Ff8[i][1], Ff8[j][1], a);
        a[0] *= cc; a[1] *= cc; a[2] *= cc; a[3] *= cc;
        acc[i][j] = a;
      }
#pragma unroll
    for (int i = 0; i < 4; ++i)
#pragma unroll
      for (int d = 0; d < 4; ++d) acc[i][i][d] = fmaf(ca, Iw[d], acc[i][i][d]);
#pragma unroll
    for (int i = 0; i < 4; ++i)
#pragma unroll
      for (int j = i; j < 4; ++j) set_half(Ff8[j][i >> 1], i & 1, cvt4rtz(acc[i][j]));
#pragma unroll
    for (int i = 0; i < 4; ++i)
#pragma unroll
      for (int j = i + 1; j < 4; ++j)
        set_half(Ff8[i][j >> 1], j & 1,
                 cvt4rtz(mfma32(Ff8[j][i >> 1], I8[i & 1], (f32x4){0.f, 0.f, 0.f, 0.f})));
#pragma unroll
    for (int i = 0; i < 4; ++i)
#pragma unroll
      for (int j = 0; j < 4; ++j) {
        f32x4 a = mfma32(Xf8[i][0], Ff8[j][0], (f32x4){0.f, 0.f, 0.f, 0.f});
        acc[i][j] = mfma32(Xf8[i][1], Ff8[j][1], a);
      }
    const bool last = (it == 5);
#pragma unroll
    for (int i = 0; i < 4; ++i)
#pragma unroll
      for (int j = 0; j < 4; ++j)
        set_half(Xf8[j][i >> 1], i & 1, last ? cvt4(acc[i][j]) : cvt4rtz(acc[i][j]));
  }

#pragma unroll
  for (int i = 0; i < 4; ++i)
#pragma unroll
    for (int c = 0; c < 2; ++c)
      *reinterpret_cast<f16x8*>(src + (i * 2 + c) * 512 + lane * 8) = Xf8[i][c];
}

// P1: G_j = sum over 16-step subchunk of eta_s * Sp_s (elementwise)
__global__ __launch_bounds__(256) void gsum_kernel(
    const float* __restrict__ eta, const _Float16* __restrict__ Mbuf,
    float* __restrict__ Gbuf, int t0, int Tc) {
  const int j = blockIdx.x, bh = blockIdx.y, tid = threadIdx.x;
  const int nsub = Tc >> 4;
  float acc[16] = {};
#pragma unroll 1
  for (int i = 0; i < 16; ++i) {
    const int tl = j * 16 + i;
    const float ev = eta[(size_t)bh * Tn + t0 + tl];
    const _Float16* sp = Mbuf + ((size_t)bh * Tc + tl) * 4096;
    const f16x8 h0 = *reinterpret_cast<const f16x8*>(sp + tid * 8);
    const f16x8 h1 = *reinterpret_cast<const f16x8*>(sp + 2048 + tid * 8);
#pragma unroll
    for (int u = 0; u < 8; ++u) {
      acc[u]     += ev * (float)h0[u];
      acc[8 + u] += ev * (float)h1[u];
    }
  }
  float* g = Gbuf + ((size_t)bh * nsub + j) * 4096;
#pragma unroll
  for (int u = 0; u < 2; ++u) {
    float4 w0 = {acc[u*4], acc[u*4+1], acc[u*4+2], acc[u*4+3]};
    *reinterpret_cast<float4*>(g + tid * 8 + u * 4) = w0;
    float4 w1 = {acc[8+u*4], acc[8+u*4+1], acc[8+u*4+2], acc[8+u*4+3]};
    *reinterpret_cast<float4*>(g + 2048 + tid * 8 + u * 4) = w1;
  }
}

// P2: scan G over 16-step subchunks -> Sbase_j; updates Scarry (elementwise)
__global__ __launch_bounds__(256) void sbase_kernel(
    float* __restrict__ Scarry, const float* __restrict__ Gbuf,
    float* __restrict__ Sbase, int Tc) {
  const int gid = blockIdx.x * 256 + threadIdx.x;   // BHn*4096
  const int bh = gid >> 12, e = gid & 4095;
  const int nsub = Tc >> 4;
  float S = Scarry[gid];
  for (int j = 0; j < nsub; ++j) {
    const size_t idx = ((size_t)bh * nsub + j) * 4096 + e;
    Sbase[idx] = S;
    S += Gbuf[idx];
  }
  Scarry[gid] = S;
}

// P3: S in registers, 16 steps, shfl_xor reduce. Frag-flat addressing.
__global__ __launch_bounds__(256) void outv2_kernel(
    const float* __restrict__ eta, const float* __restrict__ qb,
    const float* __restrict__ Sbase, const _Float16* __restrict__ Mbuf,
    float* __restrict__ ob, int t0, int Tc) {
  const int j = blockIdx.x, bh = blockIdx.y, tid = threadIdx.x;
  const int nsub = Tc >> 4;
  const int ty = tid >> 4, tx = tid & 15;
  const int dv0 = ty * 4, dk0 = tx * 4;
  int off[4];
#pragma unroll
  for (int r2 = 0; r2 < 4; ++r2) {
    const int row = dv0 + r2;
    off[r2] = ((row >> 4) * 2 + (dk0 >> 5)) * 512 +
              (((dk0 & 15) >> 2) * 16 + (row & 15)) * 8 + ((dk0 >> 4) & 1) * 4;
  }
  float S[4][4];
  const float* sb = Sbase + ((size_t)bh * nsub + j) * 4096;
#pragma unroll
  for (int r2 = 0; r2 < 4; ++r2) {
    const float4 v = *reinterpret_cast<const float4*>(sb + off[r2]);
    S[r2][0] = v.x; S[r2][1] = v.y; S[r2][2] = v.z; S[r2][3] = v.w;
  }
#pragma unroll 1
  for (int i = 0; i < 16; ++i) {
    const int tl = j * 16 + i, t = t0 + tl;
    const float ev = eta[(size_t)bh * Tn + t];
    const float4 q4 = *reinterpret_cast<const float4*>(qb + ((size_t)bh * Tn + t) * 64 + dk0);
    const _Float16* sp = Mbuf + ((size_t)bh * Tc + tl) * 4096;
    float part[4];
#pragma unroll
    for (int r2 = 0; r2 < 4; ++r2) {
      const f16x4 h = *reinterpret_cast<const f16x4*>(sp + off[r2]);
      S[r2][0] += ev * (float)h[0];
      S[r2][1] += ev * (float)h[1];
      S[r2][2] += ev * (float)h[2];
      S[r2][3] += ev * (float)h[3];
      part[r2] = S[r2][0] * q4.x + S[r2][1] * q4.y + S[r2][2] * q4.z + S[r2][3] * q4.w;
    }
#pragma unroll
    for (int m = 1; m < 16; m <<= 1)
#pragma unroll
      for (int r2 = 0; r2 < 4; ++r2) part[r2] += __shfl_xor(part[r2], m, 64);
    if (tx == 0) {
      float4 o4 = {part[0], part[1], part[2], part[3]};
      *reinterpret_cast<float4*>(ob + ((size_t)bh * Tn + t) * 64 + dv0) = o4;
    }
  }
}

// init carries; thread gid owns frag-flat element p -> map to standard (dv,dk)
__global__ __launch_bounds__(256) void init_carry_kernel(
    const float* __restrict__ S0, const float* __restrict__ M0,
    float* __restrict__ Scarry, float* __restrict__ Mcarry) {
  const int gid = blockIdx.x * 256 + threadIdx.x;
  const int h = (gid >> 12) & 7, p = gid & 4095;
  const int q = p >> 9, i = q >> 1, c = q & 1;
  const int l = (p >> 3) & 63, g = l >> 4, r = l & 15;
  const int s = p & 7, jhi = s >> 2, jlo = s & 3;
  const int dv = i * 16 + r;
  const int dk = c * 32 + jhi * 16 + g * 4 + jlo;
  const int e = dv * 64 + dk;
  Scarry[gid] = S0[h * 4096 + e];
  Mcarry[gid] = M0[h * 4096 + e];
}

// final: out = o_flat @ Wo^T via fp16 MFMA (K=32)
__global__ __launch_bounds__(256) void out_gemm_kernel(
    const float* __restrict__ ob, const float* __restrict__ Wo,
    float* __restrict__ out) {
  __shared__ __align__(16) _Float16 Af[64 * LH];
  __shared__ __align__(16) _Float16 Bf[64 * LH];
  const int tid = threadIdx.x;
  const int m0 = blockIdx.x * 64;
  const int n0 = blockIdx.y * 64;
  const int wid = tid >> 6, lane = tid & 63;
  const int r = lane & 15, g = lane >> 4;
  f32x4 acc[4] = {};
  for (int kt = 0; kt < Dn; kt += 64) {
    const int h = kt >> 6;
#pragma unroll
    for (int i = 0; i < 4; ++i) {
      const int idx = tid + (i << 8);
      const int row = idx >> 4, c4 = (idx & 15) << 2;
      const int m = m0 + row, b = m >> 10, t = m & 1023;
      const float4 v = *reinterpret_cast<const float4*>(
          ob + ((size_t)(b * Hn + h) * Tn + t) * 64 + c4);
      f16x4 hv;
      hv[0] = (_Float16)v.x; hv[1] = (_Float16)v.y; hv[2] = (_Float16)v.z; hv[3] = (_Float16)v.w;
      *reinterpret_cast<f16x4*>(Af + row * LH + c4) = hv;
    }
    stage_tile_h(Bf, Wo + (size_t)n0 * Dn + kt, Dn, tid);
    __syncthreads();
    f16x8 a8[2];
#pragma unroll
    for (int c = 0; c < 2; ++c) a8[c] = ld_frag8(Af, 16 * wid + r, c, g);
#pragma unroll
    for (int jb = 0; jb < 4; ++jb) {
#pragma unroll
      for (int c = 0; c < 2; ++c)
        acc[jb] = mfma32(a8[c], ld_frag8(Bf, 16 * jb + r, c, g), acc[jb]);
    }
    __syncthreads();
  }
#pragma unroll
  for (int jb = 0; jb < 4; ++jb)
#pragma unroll
    for (int d = 0; d < 4; ++d) {
      const int m = m0 + 16 * wid + 4 * g + d;
      const int n = n0 + 16 * jb + r;
      out[(size_t)m * Dn + n] = acc[jb][d];
    }
}

// ---------- host ----------

extern "C" void kernel_launch(void* const* d_in, const int* in_sizes, int n_in,
                              void* d_out, int out_size, void* d_ws, size_t ws_size,
                              hipStream_t stream) {
  (void)in_sizes; (void)n_in; (void)out_size;
  const float* x  = (const float*)d_in[0];
  const float* Wq = (const float*)d_in[1];
  const float* Wk = (const float*)d_in[2];
  const float* Wv = (const float*)d_in[3];
  const float* Ww = (const float*)d_in[4];
  const float* Wp = (const float*)d_in[5];
  const float* Wo = (const float*)d_in[6];
  const float* S0 = (const float*)d_in[7];
  const float* M0 = (const float*)d_in[8];
  float* out = (float*)d_out;
  float* ws  = (float*)d_ws;

  size_t off = 0;
  float* qb  = ws + off; off += (size_t)BHn * Tn * 64;
  float* kb  = ws + off; off += (size_t)BHn * Tn * 64;
  float* vb  = ws + off; off += (size_t)BHn * Tn * 64;
  float* wb  = ws + off; off += (size_t)BHn * Tn * 64;
  float* Ub  = ws + off; off += (size_t)BHn * Tn * 64;
  float* ob  = ws + off; off += (size_t)BHn * Tn * 64;
  float* eta   = ws + off; off += (size_t)BHn * Tn;
  float* theta = ws + off; off += (size_t)BHn * Tn;
  float* rowm  = ws + off; off += (size_t)BHn * Tn;
  float* rowl  = ws + off; off += (size_t)BHn * Tn;
  float* Mcarry = ws + off; off += (size_t)BHn * 4096;
  float* Scarry = ws + off; off += (size_t)BHn * 4096;
  float* TP     = ws + off; off += (size_t)BHn * (Tn / TS);

  const size_t avail0 = ws_size / sizeof(float) - off;
  int Tc = 512;
  while (Tc > TS && (size_t)BHn * Tc * 2048 + 2 * (size_t)BHn * (Tc / 16) * 4096 > avail0)
    Tc >>= 1;
  const int nsub = Tc >> 4;        // 16-step subchunks (S-scan)
  const int nsubT = Tc / TS;       // TS-step sub-blocks (M-scan)

  float* Gbuf  = ws + off; off += (size_t)BHn * nsub * 4096;   // aliases Rbuf
  float* Sbase = ws + off; off += (size_t)BHn * nsub * 4096;   // aliases Mstart
  _Float16* Mbuf = (_Float16*)(ws + off);
  float* Rbuf   = Gbuf;    // dead before gsum writes Gbuf
  float* Mstart = Sbase;   // dead before sbase writes Sbase

  hipLaunchKernelGGL(init_carry_kernel, dim3(512), dim3(256), 0, stream, S0, M0, Scarry, Mcarry);
  hipLaunchKernelGGL(proj4_kernel, dim3(64, 8, 4), dim3(256), 0, stream,
                     x, Wq, Wk, Wv, Ww, qb, kb, vb, wb);
  hipLaunchKernelGGL(wp_kernel, dim3(256), dim3(256), 0, stream, x, Wp, eta, theta);
  hipLaunchKernelGGL(thetaprod_kernel, dim3((BHn * (Tn / TS) + 255) / 256), dim3(256), 0, stream,
                     theta, TP);
  hipLaunchKernelGGL(rowstats_kernel, dim3(16, 32), dim3(256), 0, stream, wb, kb, rowm, rowl);
  hipLaunchKernelGGL(copyU_kernel, dim3(2048), dim3(256), 0, stream, vb, Ub);
  hipLaunchKernelGGL(solve_diag0_kernel, dim3(32), dim3(256), 0, stream,
                     wb, kb, vb, rowm, rowl, Ub);
  for (int ib = 0; ib < 15; ++ib) {
    hipLaunchKernelGGL(solve_step_kernel, dim3(15 - ib, 32), dim3(256), 0, stream,
                       wb, kb, rowm, rowl, Ub, ib);
  }

  for (int t0 = 0; t0 < Tn; t0 += Tc) {
    hipLaunchKernelGGL(mscanA_kernel, dim3(nsubT, BHn), dim3(256), 0, stream,
                       Ub, kb, theta, Rbuf, t0, Tc);
    hipLaunchKernelGGL(mscanB_kernel, dim3(512), dim3(256), 0, stream,
                       Mcarry, Rbuf, TP, Mstart, t0, Tc);
    hipLaunchKernelGGL(mscanC_kernel, dim3(nsubT, BHn), dim3(256), 0, stream,
                       Ub, kb, theta, Mstart, Mbuf, t0, Tc);
    hipLaunchKernelGGL(ns_kernel, dim3(BHn * Tc / 4), dim3(256), 0, stream, Mbuf);
    hipLaunchKernelGGL(gsum_kernel, dim3(nsub, BHn), dim3(256), 0, stream,
                       eta, Mbuf, Gbuf, t0, Tc);
    hipLaunchKernelGGL(sbase_kernel, dim3(512), dim3(256), 0, stream, Scarry, Gbuf, Sbase, Tc);
    hipLaunchKernelGGL(outv2_kernel, dim3(nsub, BHn), dim3(256), 0, stream,
                       eta, qb, Sbase, Mbuf, ob, t0, Tc);
  }

  hipLaunchKernelGGL(out_gemm_kernel, dim3(64, 8), dim3(256), 0, stream, ob, Wo, out);
}

// Round 14
// 1094.909 us; speedup vs baseline: 3.1949x; 1.0291x over previous
//
#include <hip/hip_runtime.h>
#include <hip/hip_bf16.h>
#include <math.h>

#define Bn 4
#define Tn 1024
#define Dn 512
#define Hn 8
#define BHn 32
#define LDP 65   // fp32 LDS stride (pad)
#define LDU 68   // fp32 LDS stride for Ua (16B-aligned rows)
#define LH 72    // fp16 LDS stride in halves
#define TS 32    // momentum scan sub-block (steps)

typedef _Float16 f16x8 __attribute__((ext_vector_type(8)));
typedef _Float16 f16x4 __attribute__((ext_vector_type(4)));
typedef float    f32x4 __attribute__((ext_vector_type(4)));

__constant__ float NS_Ac[6] = {3955.0f/1024.0f, 3735.0f/1024.0f, 3799.0f/1024.0f,
                               4019.0f/1024.0f, 2677.0f/1024.0f, 2172.0f/1024.0f};
__constant__ float NS_Bc[6] = {-8306.0f/1024.0f, -6681.0f/1024.0f, -6499.0f/1024.0f,
                               -6385.0f/1024.0f, -3029.0f/1024.0f, -1833.0f/1024.0f};
__constant__ float NS_Cc[6] = {5008.0f/1024.0f, 3463.0f/1024.0f, 3211.0f/1024.0f,
                               2906.0f/1024.0f, 1162.0f/1024.0f,  682.0f/1024.0f};

__device__ __forceinline__ f32x4 mfma16(f16x4 a, f16x4 b, f32x4 c) {
  return __builtin_amdgcn_mfma_f32_16x16x16f16(a, b, c, 0, 0, 0);
}
// K=32 MFMA; halves of operand = 16-col tiles (2c, 2c+1), k-index 4g+d.
__device__ __forceinline__ f32x4 mfma32(f16x8 a, f16x8 b, f32x4 c) {
  return __builtin_amdgcn_mfma_f32_16x16x32_f16(a, b, c, 0, 0, 0);
}

__device__ __forceinline__ f16x4 cvt4(f32x4 a) {   // RNE scalar converts
  f16x4 h;
  h[0] = (_Float16)a[0]; h[1] = (_Float16)a[1];
  h[2] = (_Float16)a[2]; h[3] = (_Float16)a[3];
  return h;
}

__device__ __forceinline__ f16x4 cvt4rtz(f32x4 a) { // packed RTZ (2 insts)
  const auto lo = __builtin_amdgcn_cvt_pkrtz(a[0], a[1]);  // __fp16 x2
  const auto hi = __builtin_amdgcn_cvt_pkrtz(a[2], a[3]);
  f16x4 h;
  h[0] = (_Float16)lo[0]; h[1] = (_Float16)lo[1];
  h[2] = (_Float16)hi[0]; h[3] = (_Float16)hi[1];
  return h;
}

__device__ __forceinline__ f16x8 pack8(f16x4 lo, f16x4 hi) {
  f16x8 o;
  o[0] = lo[0]; o[1] = lo[1]; o[2] = lo[2]; o[3] = lo[3];
  o[4] = hi[0]; o[5] = hi[1]; o[6] = hi[2]; o[7] = hi[3];
  return o;
}

__device__ __forceinline__ void set_half(f16x8& v, int h, f16x4 x) {
  if (h) { v[4] = x[0]; v[5] = x[1]; v[6] = x[2]; v[7] = x[3]; }
  else   { v[0] = x[0]; v[1] = x[1]; v[2] = x[2]; v[3] = x[3]; }
}

__device__ __forceinline__ f16x4 make_If(int r, int g) {
  const int dd = r - 4 * g;
  f16x4 If;
  If[0] = (dd == 0) ? (_Float16)1.f : (_Float16)0.f;
  If[1] = (dd == 1) ? (_Float16)1.f : (_Float16)0.f;
  If[2] = (dd == 2) ? (_Float16)1.f : (_Float16)0.f;
  If[3] = (dd == 3) ? (_Float16)1.f : (_Float16)0.f;
  return If;
}

// read f16x8 K=32 frag (row, 32-chunk c) from LDS tile [64][LH]
__device__ __forceinline__ f16x8 ld_frag8(const _Float16* lds, int row, int c, int g) {
  const f16x4 lo = *reinterpret_cast<const f16x4*>(lds + row * LH + (2 * c) * 16 + 4 * g);
  const f16x4 hi = *reinterpret_cast<const f16x4*>(lds + row * LH + (2 * c + 1) * 16 + 4 * g);
  return pack8(lo, hi);
}

// Frag-flat layout of a 64x64 matrix (4096 elements):
//   flat(row,col) = chunk*512 + lane*8 + sub
//   chunk = (row>>4)*2 + (col>>5);  lane = ((col&15)>>2)*16 + (row&15)
//   sub   = ((col>>4)&1)*4 + (col&3)

// ---------- staging helpers ----------

__device__ __forceinline__ void stage_tile_h(_Float16* __restrict__ dst,
                                             const float* __restrict__ src,
                                             int srcStride, int tid) {
#pragma unroll
  for (int i = 0; i < 4; ++i) {
    const int idx = tid + (i << 8);
    const int row = idx >> 4;
    const int c4  = (idx & 15) << 2;
    const float4 v = *reinterpret_cast<const float4*>(src + (size_t)row * srcStride + c4);
    f16x4 h;
    h[0] = (_Float16)v.x; h[1] = (_Float16)v.y; h[2] = (_Float16)v.z; h[3] = (_Float16)v.w;
    *reinterpret_cast<f16x4*>(dst + row * LH + c4) = h;
  }
}

__device__ __forceinline__ void stage_tile_u(float* __restrict__ dst,
                                             const float* __restrict__ src, int tid) {
#pragma unroll
  for (int i = 0; i < 4; ++i) {
    const int idx = tid + (i << 8);
    const int row = idx >> 4;
    const int c4  = (idx & 15) << 2;
    *reinterpret_cast<float4*>(dst + row * LDU + c4) =
        *reinterpret_cast<const float4*>(src + (size_t)row * 64 + c4);
  }
}

// Blocked unit-lower-triangular solve
__device__ __forceinline__ void tri_solve_blocked(const float* __restrict__ Sc,
                                                  float* __restrict__ Ua, int tid) {
  const int dv = tid & 63;
  const int grp = tid >> 6;
#pragma unroll 1
  for (int db = 0; db < 4; ++db) {
    const int base = db * 16;
    if (grp == 0) {
#pragma unroll 1
      for (int rr = 1; rr < 16; ++rr) {
        float s = 0.f;
        for (int c = 0; c < rr; ++c)
          s = fmaf(Sc[(base + rr) * LDP + base + c], Ua[(base + c) * LDU + dv], s);
        Ua[(base + rr) * LDU + dv] -= s;
      }
    }
    __syncthreads();
    if (db < 3) {
      for (int r2 = base + 16 + grp; r2 < 64; r2 += 4) {
        float s = 0.f;
#pragma unroll
        for (int c = 0; c < 16; ++c)
          s = fmaf(Sc[r2 * LDP + base + c], Ua[(base + c) * LDU + dv], s);
        Ua[r2 * LDU + dv] -= s;
      }
    }
    __syncthreads();
  }
}

// ---------- kernels ----------

// q/k/v/w projections via fp16 MFMA (K=32)
__global__ __launch_bounds__(256) void proj4_kernel(
    const float* __restrict__ x,
    const float* __restrict__ W0, const float* __restrict__ W1,
    const float* __restrict__ W2, const float* __restrict__ W3,
    float* __restrict__ o0, float* __restrict__ o1,
    float* __restrict__ o2, float* __restrict__ o3) {
  __shared__ __align__(16) _Float16 Af[64 * LH];
  __shared__ __align__(16) _Float16 Bf[64 * LH];
  const float* W; float* outp;
  switch (blockIdx.z) {
    case 0:  W = W0; outp = o0; break;
    case 1:  W = W1; outp = o1; break;
    case 2:  W = W2; outp = o2; break;
    default: W = W3; outp = o3; break;
  }
  const int tid = threadIdx.x;
  const int m0 = blockIdx.x * 64;
  const int n0 = blockIdx.y * 64;
  const int wid = tid >> 6, lane = tid & 63;
  const int r = lane & 15, g = lane >> 4;
  f32x4 acc[4] = {};
  for (int kt = 0; kt < Dn; kt += 64) {
    stage_tile_h(Af, x + (size_t)m0 * Dn + kt, Dn, tid);
    stage_tile_h(Bf, W + (size_t)n0 * Dn + kt, Dn, tid);
    __syncthreads();
    f16x8 a8[2];
#pragma unroll
    for (int c = 0; c < 2; ++c) a8[c] = ld_frag8(Af, 16 * wid + r, c, g);
#pragma unroll
    for (int jb = 0; jb < 4; ++jb) {
#pragma unroll
      for (int c = 0; c < 2; ++c)
        acc[jb] = mfma32(a8[c], ld_frag8(Bf, 16 * jb + r, c, g), acc[jb]);
    }
    __syncthreads();
  }
#pragma unroll
  for (int jb = 0; jb < 4; ++jb)
#pragma unroll
    for (int d = 0; d < 4; ++d) {
      const int m = m0 + 16 * wid + 4 * g + d;
      const int n = n0 + 16 * jb + r;
      const int b = m >> 10, t = m & 1023, h = n >> 6, e = n & 63;
      outp[(((size_t)(b * Hn + h)) * Tn + t) * 64 + e] = acc[jb][d];
    }
}

// eta/theta projection
#define XSTR 516
__global__ __launch_bounds__(256) void wp_kernel(const float* __restrict__ x,
                                                 const float* __restrict__ Wp,
                                                 float* __restrict__ eta,
                                                 float* __restrict__ theta) {
  __shared__ float xs[16 * XSTR];
  __shared__ float wps[16 * XSTR];
  const int tid = threadIdx.x;
  const int r0 = blockIdx.x * 16;
#pragma unroll
  for (int i = 0; i < 8; ++i) {
    const int idx = tid + (i << 8);
    const int r = idx >> 7, c4 = (idx & 127) << 2;
    const float4 v = *reinterpret_cast<const float4*>(x + (size_t)(r0 + r) * Dn + c4);
    float* p = xs + r * XSTR + c4;
    p[0] = v.x; p[1] = v.y; p[2] = v.z; p[3] = v.w;
    const float4 wv = *reinterpret_cast<const float4*>(Wp + (size_t)r * Dn + c4);
    float* pw = wps + r * XSTR + c4;
    pw[0] = wv.x; pw[1] = wv.y; pw[2] = wv.z; pw[3] = wv.w;
  }
  __syncthreads();
  const int row = tid >> 4, col = tid & 15;
  float acc = 0.f;
#pragma unroll 8
  for (int k = 0; k < Dn; ++k) acc = fmaf(xs[row * XSTR + k], wps[col * XSTR + k], acc);
  const float sg = 1.f / (1.f + __expf(-acc));
  const int m = r0 + row, b = m >> 10, t = m & 1023, h = col >> 1;
  float* dst = (col & 1) ? theta : eta;
  dst[((size_t)(b * Hn + h)) * Tn + t] = sg;
}

// Per-row softmax stats via fp16 MFMA (K=32) + wave-parallel flash update.
__global__ __launch_bounds__(256) void rowstats_kernel(
    const float* __restrict__ wb, const float* __restrict__ kb,
    float* __restrict__ rowm, float* __restrict__ rowl) {
  __shared__ __align__(16) _Float16 Wh[64 * LH];
  __shared__ __align__(16) _Float16 Kh[64 * LH];
  const int tb = blockIdx.x, bh = blockIdx.y, t0 = tb * 64;
  const int tid = threadIdx.x, wid = tid >> 6, lane = tid & 63;
  const int r = lane & 15, g = lane >> 4;
  stage_tile_h(Wh, wb + ((size_t)bh * Tn + t0) * 64, 64, tid);
  float rm[4], rl[4];
#pragma unroll
  for (int d = 0; d < 4; ++d) { rm[d] = -INFINITY; rl[d] = 0.f; }
  __syncthreads();
  f16x8 wfr8[2];
#pragma unroll
  for (int c = 0; c < 2; ++c) wfr8[c] = ld_frag8(Wh, 16 * wid + r, c, g);
  for (int sb = 0; sb <= tb; ++sb) {
    __syncthreads();
    stage_tile_h(Kh, kb + ((size_t)bh * Tn + sb * 64) * 64, 64, tid);
    __syncthreads();
    float sv[4][4];
    float tmax[4] = {-INFINITY, -INFINITY, -INFINITY, -INFINITY};
#pragma unroll
    for (int jb = 0; jb < 4; ++jb) {
      f32x4 acc = {0.f, 0.f, 0.f, 0.f};
#pragma unroll
      for (int c = 0; c < 2; ++c)
        acc = mfma32(wfr8[c], ld_frag8(Kh, 16 * jb + r, c, g), acc);
      const int col = sb * 64 + 16 * jb + r;
#pragma unroll
      for (int d = 0; d < 4; ++d) {
        const int row = t0 + 16 * wid + 4 * g + d;
        const float s = (col < row) ? acc[d] * 0.125f : -INFINITY;
        sv[jb][d] = s;
        tmax[d] = fmaxf(tmax[d], s);
      }
    }
#pragma unroll
    for (int m = 1; m < 16; m <<= 1)
#pragma unroll
      for (int d = 0; d < 4; ++d) tmax[d] = fmaxf(tmax[d], __shfl_xor(tmax[d], m, 64));
#pragma unroll
    for (int d = 0; d < 4; ++d) {
      const float mnew  = fmaxf(rm[d], tmax[d]);
      const float msafe = (mnew == -INFINITY) ? 0.f : mnew;
      float s = __expf(sv[0][d] - msafe) + __expf(sv[1][d] - msafe) +
                __expf(sv[2][d] - msafe) + __expf(sv[3][d] - msafe);
#pragma unroll
      for (int m = 1; m < 16; m <<= 1) s += __shfl_xor(s, m, 64);
      const float scale = (rm[d] == -INFINITY) ? 0.f : __expf(rm[d] - msafe);
      rl[d] = rl[d] * scale + s;
      rm[d] = mnew;
    }
  }
  if (r == 0) {
#pragma unroll
    for (int d = 0; d < 4; ++d) {
      const int row = t0 + 16 * wid + 4 * g + d;
      rowm[(size_t)bh * Tn + row] = rm[d];
      rowl[(size_t)bh * Tn + row] = (rl[d] == 0.f) ? 1.f : rl[d];
    }
  }
}

// Ub := vb
__global__ __launch_bounds__(256) void copyU_kernel(const float* __restrict__ vb,
                                                    float* __restrict__ Ub) {
  const int gid = blockIdx.x * 256 + threadIdx.x;
  ((float4*)Ub)[gid] = ((const float4*)vb)[gid];
}

// diagonal solve of block 0 (K=16 path kept)
__global__ __launch_bounds__(256) void solve_diag0_kernel(
    const float* __restrict__ wb, const float* __restrict__ kb,
    const float* __restrict__ vb, const float* __restrict__ rowm,
    const float* __restrict__ rowl, float* __restrict__ Ub) {
  __shared__ __align__(16) _Float16 Wh[64 * LH];
  __shared__ __align__(16) _Float16 Kh[64 * LH];
  __shared__ float Sc[64 * LDP];
  __shared__ __align__(16) float Ua[64 * LDU];
  __shared__ float rmL[64], rlL[64];
  const int bh = blockIdx.x;
  const int tid = threadIdx.x, wid = tid >> 6, lane = tid & 63;
  const int r = lane & 15, g = lane >> 4;
  stage_tile_h(Wh, wb + (size_t)bh * Tn * 64, 64, tid);
  stage_tile_h(Kh, kb + (size_t)bh * Tn * 64, 64, tid);
  stage_tile_u(Ua, vb + (size_t)bh * Tn * 64, tid);
  if (tid < 64) { rmL[tid] = rowm[(size_t)bh * Tn + tid]; rlL[tid] = rowl[(size_t)bh * Tn + tid]; }
  __syncthreads();
  f16x4 wfr[4];
#pragma unroll
  for (int kc = 0; kc < 4; ++kc)
    wfr[kc] = *reinterpret_cast<const f16x4*>(Wh + (16 * wid + r) * LH + kc * 16 + 4 * g);
  float rmv[4], rlv[4];
#pragma unroll
  for (int d = 0; d < 4; ++d) {
    rmv[d] = rmL[16 * wid + 4 * g + d];
    rlv[d] = rlL[16 * wid + 4 * g + d];
  }
#pragma unroll
  for (int jb = 0; jb < 4; ++jb) {
    f32x4 acc = {0.f, 0.f, 0.f, 0.f};
#pragma unroll
    for (int kc = 0; kc < 4; ++kc)
      acc = mfma16(wfr[kc],
                   *reinterpret_cast<const f16x4*>(Kh + (16 * jb + r) * LH + kc * 16 + 4 * g),
                   acc);
#pragma unroll
    for (int d = 0; d < 4; ++d) {
      const int lr = 16 * wid + 4 * g + d, lc = 16 * jb + r;
      Sc[lr * LDP + lc] = (lc < lr) ? __expf(acc[d] * 0.125f - rmv[d]) / rlv[d] : 0.f;
    }
  }
  __syncthreads();
  tri_solve_blocked(Sc, Ua, tid);
#pragma unroll
  for (int i = 0; i < 4; ++i) {
    const int idx = tid + (i << 8);
    const int row = idx >> 4, c4 = (idx & 15) << 2;
    *reinterpret_cast<float4*>(Ub + ((size_t)bh * Tn + row) * 64 + c4) =
        *reinterpret_cast<const float4*>(Ua + row * LDU + c4);
  }
}

// step ib: U[f] -= P[f,ib] @ U[ib]; f==ib+1 also diag-solves (K=16 path kept)
__global__ __launch_bounds__(256) void solve_step_kernel(
    const float* __restrict__ wb, const float* __restrict__ kb,
    const float* __restrict__ rowm, const float* __restrict__ rowl,
    float* __restrict__ Ub, int ib) {
  __shared__ __align__(16) _Float16 Wh[64 * LH];
  __shared__ __align__(16) _Float16 Kh[64 * LH];
  __shared__ __align__(16) _Float16 UTh[64 * LH];
  __shared__ float Sc[64 * LDP];
  __shared__ __align__(16) float Ua[64 * LDU];
  __shared__ float rmL[64], rlL[64];
  const int f = ib + 1 + blockIdx.x, bh = blockIdx.y;
  const int tid = threadIdx.x, wid = tid >> 6, lane = tid & 63;
  const int r = lane & 15, g = lane >> 4;
  stage_tile_h(Wh, wb + ((size_t)bh * Tn + f * 64) * 64, 64, tid);
  stage_tile_h(Kh, kb + ((size_t)bh * Tn + ib * 64) * 64, 64, tid);
  {
    const float* src = Ub + ((size_t)bh * Tn + ib * 64) * 64;
#pragma unroll
    for (int i2 = 0; i2 < 4; ++i2) {
      const int idx = tid + (i2 << 8);
      const int row = idx >> 4, c4 = (idx & 15) << 2;
      const float4 v = *reinterpret_cast<const float4*>(src + (size_t)row * 64 + c4);
      UTh[(c4 + 0) * LH + row] = (_Float16)v.x;
      UTh[(c4 + 1) * LH + row] = (_Float16)v.y;
      UTh[(c4 + 2) * LH + row] = (_Float16)v.z;
      UTh[(c4 + 3) * LH + row] = (_Float16)v.w;
    }
  }
  if (tid < 64) {
    rmL[tid] = rowm[(size_t)bh * Tn + f * 64 + tid];
    rlL[tid] = rowl[(size_t)bh * Tn + f * 64 + tid];
  }
  __syncthreads();
  f16x4 wfr[4];
#pragma unroll
  for (int kc = 0; kc < 4; ++kc)
    wfr[kc] = *reinterpret_cast<const f16x4*>(Wh + (16 * wid + r) * LH + kc * 16 + 4 * g);
  float rmv[4], rlv[4];
#pragma unroll
  for (int d = 0; d < 4; ++d) {
    rmv[d] = rmL[16 * wid + 4 * g + d];
    rlv[d] = rlL[16 * wid + 4 * g + d];
  }
  const f16x4 If = make_If(r, g);
  f16x4 Pfr[4];
#pragma unroll
  for (int jb = 0; jb < 4; ++jb) {
    f32x4 acc = {0.f, 0.f, 0.f, 0.f};
#pragma unroll
    for (int kc = 0; kc < 4; ++kc)
      acc = mfma16(wfr[kc],
                   *reinterpret_cast<const f16x4*>(Kh + (16 * jb + r) * LH + kc * 16 + 4 * g),
                   acc);
    f16x4 pf;
#pragma unroll
    for (int d = 0; d < 4; ++d)
      pf[d] = (_Float16)(-__expf(acc[d] * 0.125f - rmv[d]) / rlv[d]);
    Pfr[jb] = cvt4(mfma16(pf, If, (f32x4){0.f, 0.f, 0.f, 0.f}));
  }
  const float* uf = Ub + ((size_t)bh * Tn + f * 64) * 64;
  f32x4 acc2[4];
#pragma unroll
  for (int i = 0; i < 4; ++i) {
    const float4 v = *reinterpret_cast<const float4*>(uf + (size_t)(16 * wid + r) * 64 + 16 * i + 4 * g);
    acc2[i][0] = v.x; acc2[i][1] = v.y; acc2[i][2] = v.z; acc2[i][3] = v.w;
#pragma unroll
    for (int kc = 0; kc < 4; ++kc)
      acc2[i] = mfma16(*reinterpret_cast<const f16x4*>(UTh + (16 * i + r) * LH + kc * 16 + 4 * g),
                       Pfr[kc], acc2[i]);
  }
  if (f == ib + 1) {
    __syncthreads();
    stage_tile_h(Kh, kb + ((size_t)bh * Tn + f * 64) * 64, 64, tid);
#pragma unroll
    for (int i = 0; i < 4; ++i) {
      float4 v = {acc2[i][0], acc2[i][1], acc2[i][2], acc2[i][3]};
      *reinterpret_cast<float4*>(Ua + (16 * wid + r) * LDU + 16 * i + 4 * g) = v;
    }
    __syncthreads();
#pragma unroll
    for (int jb = 0; jb < 4; ++jb) {
      f32x4 acc = {0.f, 0.f, 0.f, 0.f};
#pragma unroll
      for (int kc = 0; kc < 4; ++kc)
        acc = mfma16(wfr[kc],
                     *reinterpret_cast<const f16x4*>(Kh + (16 * jb + r) * LH + kc * 16 + 4 * g),
                     acc);
#pragma unroll
      for (int d = 0; d < 4; ++d) {
        const int lr = 16 * wid + 4 * g + d, lc = 16 * jb + r;
        Sc[lr * LDP + lc] = (lc < lr) ? __expf(acc[d] * 0.125f - rmv[d]) / rlv[d] : 0.f;
      }
    }
    __syncthreads();
    tri_solve_blocked(Sc, Ua, tid);
#pragma unroll
    for (int i2 = 0; i2 < 4; ++i2) {
      const int idx = tid + (i2 << 8);
      const int row = idx >> 4, c4 = (idx & 15) << 2;
      *reinterpret_cast<float4*>(Ub + ((size_t)bh * Tn + f * 64 + row) * 64 + c4) =
          *reinterpret_cast<const float4*>(Ua + row * LDU + c4);
    }
  } else {
#pragma unroll
    for (int i = 0; i < 4; ++i) {
      float4 v = {acc2[i][0], acc2[i][1], acc2[i][2], acc2[i][3]};
      *reinterpret_cast<float4*>(Ub + ((size_t)bh * Tn + f * 64 + 16 * wid + r) * 64 + 16 * i + 4 * g) = v;
    }
  }
}

// theta block-products: TP[bh][jg] = prod of theta over [jg*TS, (jg+1)*TS)
__global__ __launch_bounds__(256) void thetaprod_kernel(
    const float* __restrict__ theta, float* __restrict__ TP) {
  const int idx = blockIdx.x * 256 + threadIdx.x;   // BHn * (Tn/TS)
  if (idx >= BHn * (Tn / TS)) return;
  const int bh = idx / (Tn / TS), jg = idx % (Tn / TS);
  const float* th = theta + (size_t)bh * Tn + jg * TS;
  float p = 1.f;
#pragma unroll
  for (int s = 0; s < TS; ++s) p *= th[s];
  TP[idx] = p;
}

// Phase A: R_j = recurrence over TS steps from ZERO init. 16 elems/thread.
__global__ __launch_bounds__(256) void mscanA_kernel(
    const float* __restrict__ Ub, const float* __restrict__ kb,
    const float* __restrict__ theta, float* __restrict__ Rbuf,
    int t0, int Tc) {
  const int j = blockIdx.x, bh = blockIdx.y, tid = threadIdx.x;
  const int nsub = Tc / TS;
  const int chunk = tid >> 5, l0 = (2 * tid) & 63;
  const int i = chunk >> 1, c = chunk & 1, g = l0 >> 4;
  const int dv0 = i * 16 + (l0 & 15);           // even; owns dv0, dv0+1
  const int kbase = c * 32 + g * 4;
  const int tb = t0 + j * TS;
  const float* Urow = Ub + ((size_t)bh * Tn + tb) * 64;
  const float* krow = kb + ((size_t)bh * Tn + tb) * 64;
  const float* th   = theta + (size_t)bh * Tn + tb;
  float M[2][8] = {};
#pragma unroll 2
  for (int st = 0; st < TS; ++st) {
    const float thv = th[st], om = 1.f - thv;
    const float2 uv = *reinterpret_cast<const float2*>(Urow + (size_t)st * 64 + dv0);
    const float4 k0 = *reinterpret_cast<const float4*>(krow + (size_t)st * 64 + kbase);
    const float4 k1 = *reinterpret_cast<const float4*>(krow + (size_t)st * 64 + kbase + 16);
    const float kv[8] = {k0.x, k0.y, k0.z, k0.w, k1.x, k1.y, k1.z, k1.w};
    const float ou[2] = {om * uv.x, om * uv.y};
#pragma unroll
    for (int gq = 0; gq < 2; ++gq)
#pragma unroll
      for (int s = 0; s < 8; ++s)
        M[gq][s] = fmaf(thv, M[gq][s], ou[gq] * kv[s]);
  }
  float* rp = Rbuf + ((size_t)bh * nsub + j) * 4096 + tid * 16;
#pragma unroll
  for (int gq = 0; gq < 2; ++gq)
#pragma unroll
    for (int h = 0; h < 2; ++h) {
      float4 v = {M[gq][h*4], M[gq][h*4+1], M[gq][h*4+2], M[gq][h*4+3]};
      *reinterpret_cast<float4*>(rp + gq * 8 + h * 4) = v;
    }
}

// Phase B: elementwise scan over sub-blocks: Mstart[j] = M; M = TP_j*M + R_j.
__global__ __launch_bounds__(256) void mscanB_kernel(
    float* __restrict__ Mcarry, const float* __restrict__ Rbuf,
    const float* __restrict__ TP, float* __restrict__ Mstart,
    int t0, int Tc) {
  const int gid = blockIdx.x * 256 + threadIdx.x;   // BHn*4096
  const int bh = gid >> 12, p = gid & 4095;
  const int nsub = Tc / TS;
  const int jg0 = t0 / TS;
  float M = Mcarry[gid];
  for (int j = 0; j < nsub; ++j) {
    const size_t idx = ((size_t)bh * nsub + j) * 4096 + p;
    Mstart[idx] = M;
    M = TP[bh * (Tn / TS) + jg0 + j] * M + Rbuf[idx];
  }
  Mcarry[gid] = M;
}

// Phase C: regenerate TS steps from Mstart, write fp16 Mbuf (2 f16x8/step).
__global__ __launch_bounds__(256) void mscanC_kernel(
    const float* __restrict__ Ub, const float* __restrict__ kb,
    const float* __restrict__ theta, const float* __restrict__ Mstart,
    _Float16* __restrict__ Mbuf, int t0, int Tc) {
  const int j = blockIdx.x, bh = blockIdx.y, tid = threadIdx.x;
  const int nsub = Tc / TS;
  const int chunk = tid >> 5, l0 = (2 * tid) & 63;
  const int i = chunk >> 1, c = chunk & 1, g = l0 >> 4;
  const int dv0 = i * 16 + (l0 & 15);
  const int kbase = c * 32 + g * 4;
  const int tb = t0 + j * TS;
  const float* Urow = Ub + ((size_t)bh * Tn + tb) * 64;
  const float* krow = kb + ((size_t)bh * Tn + tb) * 64;
  const float* th   = theta + (size_t)bh * Tn + tb;
  float M[2][8];
  const float* mp = Mstart + ((size_t)bh * nsub + j) * 4096 + tid * 16;
#pragma unroll
  for (int gq = 0; gq < 2; ++gq)
#pragma unroll
    for (int h = 0; h < 2; ++h) {
      const float4 v = *reinterpret_cast<const float4*>(mp + gq * 8 + h * 4);
      M[gq][h*4] = v.x; M[gq][h*4+1] = v.y; M[gq][h*4+2] = v.z; M[gq][h*4+3] = v.w;
    }
#pragma unroll 2
  for (int st = 0; st < TS; ++st) {
    const float thv = th[st], om = 1.f - thv;
    const float2 uv = *reinterpret_cast<const float2*>(Urow + (size_t)st * 64 + dv0);
    const float4 k0 = *reinterpret_cast<const float4*>(krow + (size_t)st * 64 + kbase);
    const float4 k1 = *reinterpret_cast<const float4*>(krow + (size_t)st * 64 + kbase + 16);
    const float kv[8] = {k0.x, k0.y, k0.z, k0.w, k1.x, k1.y, k1.z, k1.w};
    const float ou[2] = {om * uv.x, om * uv.y};
    _Float16* dst = Mbuf + ((size_t)bh * Tc + j * TS + st) * 4096 + tid * 16;
#pragma unroll
    for (int gq = 0; gq < 2; ++gq) {
      f16x8 hh;
#pragma unroll
      for (int s = 0; s < 8; ++s) {
        M[gq][s] = fmaf(thv, M[gq][s], ou[gq] * kv[s]);
        hh[s] = (_Float16)M[gq][s];
      }
      *reinterpret_cast<f16x8*>(dst + gq * 8) = hh;
    }
  }
}

// Newton-Schulz (6 iters), ONE WAVE per 64x64 matrix, register-resident, K=32.
// Zero LDS; frag-flat Mbuf; packed RTZ converts; final X' in RNE.
// Needs ~160 VGPR: min-waves 3 (cap 170, no spill). 4 (cap 128) spills ~32 regs
// (R13: +132MB scratch writes); 8 (cap 64) catastrophically spills (R12).
__global__ __launch_bounds__(256, 3) void ns_kernel(_Float16* __restrict__ Mbuf) {
  const int tid  = threadIdx.x;
  const int wid  = tid >> 6, lane = tid & 63;
  const int r    = lane & 15, g = lane >> 4;
  _Float16* src = Mbuf + ((size_t)blockIdx.x * 4 + wid) * 4096;

  f16x8 Xf8[4][2];
  float ss = 0.f;
#pragma unroll
  for (int i = 0; i < 4; ++i)
#pragma unroll
    for (int c = 0; c < 2; ++c) {
      const f16x8 h = *reinterpret_cast<const f16x8*>(src + (i * 2 + c) * 512 + lane * 8);
#pragma unroll
      for (int d = 0; d < 8; ++d) { const float f = (float)h[d]; ss += f * f; }
      Xf8[i][c] = h;
    }
#pragma unroll
  for (int off = 32; off > 0; off >>= 1) ss += __shfl_xor(ss, off, 64);
  const float inv = 1.f / (sqrtf(ss) + 1e-7f);
#pragma unroll
  for (int i = 0; i < 4; ++i)
#pragma unroll
    for (int c = 0; c < 2; ++c) {
      f32x4 lo, hi;
#pragma unroll
      for (int d = 0; d < 4; ++d) { lo[d] = (float)Xf8[i][c][d] * inv; hi[d] = (float)Xf8[i][c][d + 4] * inv; }
      Xf8[i][c] = pack8(cvt4rtz(lo), cvt4rtz(hi));
    }

  const f16x4 If = make_If(r, g);
  f16x4 zero4;
  zero4[0] = (_Float16)0.f; zero4[1] = (_Float16)0.f;
  zero4[2] = (_Float16)0.f; zero4[3] = (_Float16)0.f;
  const f16x8 I8[2] = {pack8(If, zero4), pack8(zero4, If)};
  float Iw[4];
  Iw[0] = (float)If[0]; Iw[1] = (float)If[1]; Iw[2] = (float)If[2]; Iw[3] = (float)If[3];

  f16x8 Ff8[4][2];
  f32x4 acc[4][4];

#pragma unroll 1
  for (int it = 0; it < 6; ++it) {
    const float ca = NS_Ac[it], cb = NS_Bc[it], cc = NS_Cc[it];
#pragma unroll
    for (int i = 0; i < 4; ++i)
#pragma unroll
      for (int j = i; j < 4; ++j) {
        f32x4 a = mfma32(Xf8[i][0], Xf8[j][0], (f32x4){0.f, 0.f, 0.f, 0.f});
        acc[i][j] = mfma32(Xf8[i][1], Xf8[j][1], a);
      }
#pragma unroll
    for (int i = 0; i < 4; ++i) {
      {
        const f16x4 t = cvt4rtz(mfma32(Xf8[i][i >> 1], I8[i & 1], (f32x4){0.f, 0.f, 0.f, 0.f}));
        set_half(Xf8[i][i >> 1], i & 1, t);
      }
#pragma unroll
      for (int j = i + 1; j < 4; ++j) {
        const f16x4 t1 = cvt4rtz(mfma32(Xf8[i][j >> 1], I8[j & 1], (f32x4){0.f, 0.f, 0.f, 0.f}));
        const f16x4 t2 = cvt4rtz(mfma32(Xf8[j][i >> 1], I8[i & 1], (f32x4){0.f, 0.f, 0.f, 0.f}));
        set_half(Xf8[j][i >> 1], i & 1, t1);
        set_half(Xf8[i][j >> 1], j & 1, t2);
      }
    }
#pragma unroll
    for (int i = 0; i < 4; ++i)
#pragma unroll
      for (int j = i; j < 4; ++j) set_half(Ff8[j][i >> 1], i & 1, cvt4rtz(acc[i][j]));
#pragma unroll
    for (int i = 0; i < 4; ++i)
#pragma unroll
      for (int j = i + 1; j < 4; ++j)
        set_half(Ff8[i][j >> 1], j & 1,
                 cvt4rtz(mfma32(Ff8[j][i >> 1], I8[i & 1], (f32x4){0.f, 0.f, 0.f, 0.f})));
    const float bc = cb / cc;
#pragma unroll
    for (int i = 0; i < 4; ++i)
#pragma unroll
      for (int j = i; j < 4; ++j) {
        f32x4 a = acc[i][j];
        a[0] *= bc; a[1] *= bc; a[2] *= bc; a[3] *= bc;
        a = mfma32(Ff8[i][0], Ff8[j][0], a);
        a = mfma32(Ff8[i][1], Ff8[j][1], a);
        a[0] *= cc; a[1] *= cc; a[2] *= cc; a[3] *= cc;
        acc[i][j] = a;
      }
#pragma unroll
    for (int i = 0; i < 4; ++i)
#pragma unroll
      for (int d = 0; d < 4; ++d) acc[i][i][d] = fmaf(ca, Iw[d], acc[i][i][d]);
#pragma unroll
    for (int i = 0; i < 4; ++i)
#pragma unroll
      for (int j = i; j < 4; ++j) set_half(Ff8[j][i >> 1], i & 1, cvt4rtz(acc[i][j]));
#pragma unroll
    for (int i = 0; i < 4; ++i)
#pragma unroll
      for (int j = i + 1; j < 4; ++j)
        set_half(Ff8[i][j >> 1], j & 1,
                 cvt4rtz(mfma32(Ff8[j][i >> 1], I8[i & 1], (f32x4){0.f, 0.f, 0.f, 0.f})));
#pragma unroll
    for (int i = 0; i < 4; ++i)
#pragma unroll
      for (int j = 0; j < 4; ++j) {
        f32x4 a = mfma32(Xf8[i][0], Ff8[j][0], (f32x4){0.f, 0.f, 0.f, 0.f});
        acc[i][j] = mfma32(Xf8[i][1], Ff8[j][1], a);
      }
    const bool last = (it == 5);
#pragma unroll
    for (int i = 0; i < 4; ++i)
#pragma unroll
      for (int j = 0; j < 4; ++j)
        set_half(Xf8[j][i >> 1], i & 1, last ? cvt4(acc[i][j]) : cvt4rtz(acc[i][j]));
  }

#pragma unroll
  for (int i = 0; i < 4; ++i)
#pragma unroll
    for (int c = 0; c < 2; ++c)
      *reinterpret_cast<f16x8*>(src + (i * 2 + c) * 512 + lane * 8) = Xf8[i][c];
}

// P1: G_j = sum over 16-step subchunk of eta_s * Sp_s (elementwise)
__global__ __launch_bounds__(256) void gsum_kernel(
    const float* __restrict__ eta, const _Float16* __restrict__ Mbuf,
    float* __restrict__ Gbuf, int t0, int Tc) {
  const int j = blockIdx.x, bh = blockIdx.y, tid = threadIdx.x;
  const int nsub = Tc >> 4;
  float acc[16] = {};
#pragma unroll 1
  for (int i = 0; i < 16; ++i) {
    const int tl = j * 16 + i;
    const float ev = eta[(size_t)bh * Tn + t0 + tl];
    const _Float16* sp = Mbuf + ((size_t)bh * Tc + tl) * 4096;
    const f16x8 h0 = *reinterpret_cast<const f16x8*>(sp + tid * 8);
    const f16x8 h1 = *reinterpret_cast<const f16x8*>(sp + 2048 + tid * 8);
#pragma unroll
    for (int u = 0; u < 8; ++u) {
      acc[u]     += ev * (float)h0[u];
      acc[8 + u] += ev * (float)h1[u];
    }
  }
  float* g = Gbuf + ((size_t)bh * nsub + j) * 4096;
#pragma unroll
  for (int u = 0; u < 2; ++u) {
    float4 w0 = {acc[u*4], acc[u*4+1], acc[u*4+2], acc[u*4+3]};
    *reinterpret_cast<float4*>(g + tid * 8 + u * 4) = w0;
    float4 w1 = {acc[8+u*4], acc[8+u*4+1], acc[8+u*4+2], acc[8+u*4+3]};
    *reinterpret_cast<float4*>(g + 2048 + tid * 8 + u * 4) = w1;
  }
}

// P2: scan G over 16-step subchunks -> Sbase_j; updates Scarry (elementwise)
__global__ __launch_bounds__(256) void sbase_kernel(
    float* __restrict__ Scarry, const float* __restrict__ Gbuf,
    float* __restrict__ Sbase, int Tc) {
  const int gid = blockIdx.x * 256 + threadIdx.x;   // BHn*4096
  const int bh = gid >> 12, e = gid & 4095;
  const int nsub = Tc >> 4;
  float S = Scarry[gid];
  for (int j = 0; j < nsub; ++j) {
    const size_t idx = ((size_t)bh * nsub + j) * 4096 + e;
    Sbase[idx] = S;
    S += Gbuf[idx];
  }
  Scarry[gid] = S;
}

// P3: S in registers, 16 steps, shfl_xor reduce. Frag-flat addressing.
__global__ __launch_bounds__(256) void outv2_kernel(
    const float* __restrict__ eta, const float* __restrict__ qb,
    const float* __restrict__ Sbase, const _Float16* __restrict__ Mbuf,
    float* __restrict__ ob, int t0, int Tc) {
  const int j = blockIdx.x, bh = blockIdx.y, tid = threadIdx.x;
  const int nsub = Tc >> 4;
  const int ty = tid >> 4, tx = tid & 15;
  const int dv0 = ty * 4, dk0 = tx * 4;
  int off[4];
#pragma unroll
  for (int r2 = 0; r2 < 4; ++r2) {
    const int row = dv0 + r2;
    off[r2] = ((row >> 4) * 2 + (dk0 >> 5)) * 512 +
              (((dk0 & 15) >> 2) * 16 + (row & 15)) * 8 + ((dk0 >> 4) & 1) * 4;
  }
  float S[4][4];
  const float* sb = Sbase + ((size_t)bh * nsub + j) * 4096;
#pragma unroll
  for (int r2 = 0; r2 < 4; ++r2) {
    const float4 v = *reinterpret_cast<const float4*>(sb + off[r2]);
    S[r2][0] = v.x; S[r2][1] = v.y; S[r2][2] = v.z; S[r2][3] = v.w;
  }
#pragma unroll 1
  for (int i = 0; i < 16; ++i) {
    const int tl = j * 16 + i, t = t0 + tl;
    const float ev = eta[(size_t)bh * Tn + t];
    const float4 q4 = *reinterpret_cast<const float4*>(qb + ((size_t)bh * Tn + t) * 64 + dk0);
    const _Float16* sp = Mbuf + ((size_t)bh * Tc + tl) * 4096;
    float part[4];
#pragma unroll
    for (int r2 = 0; r2 < 4; ++r2) {
      const f16x4 h = *reinterpret_cast<const f16x4*>(sp + off[r2]);
      S[r2][0] += ev * (float)h[0];
      S[r2][1] += ev * (float)h[1];
      S[r2][2] += ev * (float)h[2];
      S[r2][3] += ev * (float)h[3];
      part[r2] = S[r2][0] * q4.x + S[r2][1] * q4.y + S[r2][2] * q4.z + S[r2][3] * q4.w;
    }
#pragma unroll
    for (int m = 1; m < 16; m <<= 1)
#pragma unroll
      for (int r2 = 0; r2 < 4; ++r2) part[r2] += __shfl_xor(part[r2], m, 64);
    if (tx == 0) {
      float4 o4 = {part[0], part[1], part[2], part[3]};
      *reinterpret_cast<float4*>(ob + ((size_t)bh * Tn + t) * 64 + dv0) = o4;
    }
  }
}

// init carries; thread gid owns frag-flat element p -> map to standard (dv,dk)
__global__ __launch_bounds__(256) void init_carry_kernel(
    const float* __restrict__ S0, const float* __restrict__ M0,
    float* __restrict__ Scarry, float* __restrict__ Mcarry) {
  const int gid = blockIdx.x * 256 + threadIdx.x;
  const int h = (gid >> 12) & 7, p = gid & 4095;
  const int q = p >> 9, i = q >> 1, c = q & 1;
  const int l = (p >> 3) & 63, g = l >> 4, r = l & 15;
  const int s = p & 7, jhi = s >> 2, jlo = s & 3;
  const int dv = i * 16 + r;
  const int dk = c * 32 + jhi * 16 + g * 4 + jlo;
  const int e = dv * 64 + dk;
  Scarry[gid] = S0[h * 4096 + e];
  Mcarry[gid] = M0[h * 4096 + e];
}

// final: out = o_flat @ Wo^T via fp16 MFMA (K=32)
__global__ __launch_bounds__(256) void out_gemm_kernel(
    const float* __restrict__ ob, const float* __restrict__ Wo,
    float* __restrict__ out) {
  __shared__ __align__(16) _Float16 Af[64 * LH];
  __shared__ __align__(16) _Float16 Bf[64 * LH];
  const int tid = threadIdx.x;
  const int m0 = blockIdx.x * 64;
  const int n0 = blockIdx.y * 64;
  const int wid = tid >> 6, lane = tid & 63;
  const int r = lane & 15, g = lane >> 4;
  f32x4 acc[4] = {};
  for (int kt = 0; kt < Dn; kt += 64) {
    const int h = kt >> 6;
#pragma unroll
    for (int i = 0; i < 4; ++i) {
      const int idx = tid + (i << 8);
      const int row = idx >> 4, c4 = (idx & 15) << 2;
      const int m = m0 + row, b = m >> 10, t = m & 1023;
      const float4 v = *reinterpret_cast<const float4*>(
          ob + ((size_t)(b * Hn + h) * Tn + t) * 64 + c4);
      f16x4 hv;
      hv[0] = (_Float16)v.x; hv[1] = (_Float16)v.y; hv[2] = (_Float16)v.z; hv[3] = (_Float16)v.w;
      *reinterpret_cast<f16x4*>(Af + row * LH + c4) = hv;
    }
    stage_tile_h(Bf, Wo + (size_t)n0 * Dn + kt, Dn, tid);
    __syncthreads();
    f16x8 a8[2];
#pragma unroll
    for (int c = 0; c < 2; ++c) a8[c] = ld_frag8(Af, 16 * wid + r, c, g);
#pragma unroll
    for (int jb = 0; jb < 4; ++jb) {
#pragma unroll
      for (int c = 0; c < 2; ++c)
        acc[jb] = mfma32(a8[c], ld_frag8(Bf, 16 * jb + r, c, g), acc[jb]);
    }
    __syncthreads();
  }
#pragma unroll
  for (int jb = 0; jb < 4; ++jb)
#pragma unroll
    for (int d = 0; d < 4; ++d) {
      const int m = m0 + 16 * wid + 4 * g + d;
      const int n = n0 + 16 * jb + r;
      out[(size_t)m * Dn + n] = acc[jb][d];
    }
}

// ---------- host ----------

extern "C" void kernel_launch(void* const* d_in, const int* in_sizes, int n_in,
                              void* d_out, int out_size, void* d_ws, size_t ws_size,
                              hipStream_t stream) {
  (void)in_sizes; (void)n_in; (void)out_size;
  const float* x  = (const float*)d_in[0];
  const float* Wq = (const float*)d_in[1];
  const float* Wk = (const float*)d_in[2];
  const float* Wv = (const float*)d_in[3];
  const float* Ww = (const float*)d_in[4];
  const float* Wp = (const float*)d_in[5];
  const float* Wo = (const float*)d_in[6];
  const float* S0 = (const float*)d_in[7];
  const float* M0 = (const float*)d_in[8];
  float* out = (float*)d_out;
  float* ws  = (float*)d_ws;

  size_t off = 0;
  float* qb  = ws + off; off += (size_t)BHn * Tn * 64;
  float* kb  = ws + off; off += (size_t)BHn * Tn * 64;
  float* vb  = ws + off; off += (size_t)BHn * Tn * 64;
  float* wb  = ws + off; off += (size_t)BHn * Tn * 64;
  float* Ub  = ws + off; off += (size_t)BHn * Tn * 64;
  float* ob  = ws + off; off += (size_t)BHn * Tn * 64;
  float* eta   = ws + off; off += (size_t)BHn * Tn;
  float* theta = ws + off; off += (size_t)BHn * Tn;
  float* rowm  = ws + off; off += (size_t)BHn * Tn;
  float* rowl  = ws + off; off += (size_t)BHn * Tn;
  float* Mcarry = ws + off; off += (size_t)BHn * 4096;
  float* Scarry = ws + off; off += (size_t)BHn * 4096;
  float* TP     = ws + off; off += (size_t)BHn * (Tn / TS);

  const size_t avail0 = ws_size / sizeof(float) - off;
  int Tc = 512;
  while (Tc > TS && (size_t)BHn * Tc * 2048 + 2 * (size_t)BHn * (Tc / 16) * 4096 > avail0)
    Tc >>= 1;
  const int nsub = Tc >> 4;        // 16-step subchunks (S-scan)
  const int nsubT = Tc / TS;       // TS-step sub-blocks (M-scan)

  float* Gbuf  = ws + off; off += (size_t)BHn * nsub * 4096;   // aliases Rbuf
  float* Sbase = ws + off; off += (size_t)BHn * nsub * 4096;   // aliases Mstart
  _Float16* Mbuf = (_Float16*)(ws + off);
  float* Rbuf   = Gbuf;    // dead before gsum writes Gbuf
  float* Mstart = Sbase;   // dead before sbase writes Sbase

  hipLaunchKernelGGL(init_carry_kernel, dim3(512), dim3(256), 0, stream, S0, M0, Scarry, Mcarry);
  hipLaunchKernelGGL(proj4_kernel, dim3(64, 8, 4), dim3(256), 0, stream,
                     x, Wq, Wk, Wv, Ww, qb, kb, vb, wb);
  hipLaunchKernelGGL(wp_kernel, dim3(256), dim3(256), 0, stream, x, Wp, eta, theta);
  hipLaunchKernelGGL(thetaprod_kernel, dim3((BHn * (Tn / TS) + 255) / 256), dim3(256), 0, stream,
                     theta, TP);
  hipLaunchKernelGGL(rowstats_kernel, dim3(16, 32), dim3(256), 0, stream, wb, kb, rowm, rowl);
  hipLaunchKernelGGL(copyU_kernel, dim3(2048), dim3(256), 0, stream, vb, Ub);
  hipLaunchKernelGGL(solve_diag0_kernel, dim3(32), dim3(256), 0, stream,
                     wb, kb, vb, rowm, rowl, Ub);
  for (int ib = 0; ib < 15; ++ib) {
    hipLaunchKernelGGL(solve_step_kernel, dim3(15 - ib, 32), dim3(256), 0, stream,
                       wb, kb, rowm, rowl, Ub, ib);
  }

  for (int t0 = 0; t0 < Tn; t0 += Tc) {
    hipLaunchKernelGGL(mscanA_kernel, dim3(nsubT, BHn), dim3(256), 0, stream,
                       Ub, kb, theta, Rbuf, t0, Tc);
    hipLaunchKernelGGL(mscanB_kernel, dim3(512), dim3(256), 0, stream,
                       Mcarry, Rbuf, TP, Mstart, t0, Tc);
    hipLaunchKernelGGL(mscanC_kernel, dim3(nsubT, BHn), dim3(256), 0, stream,
                       Ub, kb, theta, Mstart, Mbuf, t0, Tc);
    hipLaunchKernelGGL(ns_kernel, dim3(BHn * Tc / 4), dim3(256), 0, stream, Mbuf);
    hipLaunchKernelGGL(gsum_kernel, dim3(nsub, BHn), dim3(256), 0, stream,
                       eta, Mbuf, Gbuf, t0, Tc);
    hipLaunchKernelGGL(sbase_kernel, dim3(512), dim3(256), 0, stream, Scarry, Gbuf, Sbase, Tc);
    hipLaunchKernelGGL(outv2_kernel, dim3(nsub, BHn), dim3(256), 0, stream,
                       eta, qb, Sbase, Mbuf, ob, t0, Tc);
  }

  hipLaunchKernelGGL(out_gemm_kernel, dim3(64, 8), dim3(256), 0, stream, ob, Wo, out);
}